// Round 1
// baseline (10885.461 us; speedup 1.0000x reference)
//
#include <hip/hip_runtime.h>
#include <hip/hip_bf16.h>
#include <math.h>

// ---------- types ----------
typedef __attribute__((ext_vector_type(8))) short      bf16x8;
typedef __attribute__((ext_vector_type(8))) unsigned short ushort8;
typedef __attribute__((ext_vector_type(4))) float      f32x4;

__device__ __forceinline__ unsigned short f2bf(float f) {
    union { float f; unsigned u; } v; v.f = f;
    unsigned u = v.u;
    unsigned r = (u + 0x7FFFu + ((u >> 16) & 1u)) >> 16;   // RNE
    return (unsigned short)r;
}

// ---------- LayerNorm over last dim = 768 ----------
// one block (256 threads) per row; remap!=0 re-places patch rows into the
// (b,1024,d) layout leaving row 0 of each batch for the cls token.
__global__ __launch_bounds__(256) void ln768_k(const float* __restrict__ in,
                                               const float* __restrict__ g,
                                               const float* __restrict__ b,
                                               float* __restrict__ out,
                                               int remap) {
    int r = blockIdx.x, tid = threadIdx.x;
    const float* x = in + (size_t)r * 768;
    float v0 = x[tid], v1 = x[tid + 256], v2 = x[tid + 512];
    __shared__ float red[4];
    float s = v0 + v1 + v2;
    #pragma unroll
    for (int off = 32; off > 0; off >>= 1) s += __shfl_down(s, off);
    if ((tid & 63) == 0) red[tid >> 6] = s;
    __syncthreads();
    float mean = (red[0] + red[1] + red[2] + red[3]) * (1.0f / 768.0f);
    float d0 = v0 - mean, d1 = v1 - mean, d2 = v2 - mean;
    float q = d0 * d0 + d1 * d1 + d2 * d2;
    __syncthreads();
    #pragma unroll
    for (int off = 32; off > 0; off >>= 1) q += __shfl_down(q, off);
    if ((tid & 63) == 0) red[tid >> 6] = q;
    __syncthreads();
    float var = (red[0] + red[1] + red[2] + red[3]) * (1.0f / 768.0f);
    float rs = rsqrtf(var + 1e-5f);
    int orow = remap ? ((r / 1023) * 1024 + 1 + (r % 1023)) : r;
    float* y = out + (size_t)orow * 768;
    y[tid]       = d0 * rs * g[tid]       + b[tid];
    y[tid + 256] = d1 * rs * g[tid + 256] + b[tid + 256];
    y[tid + 512] = d2 * rs * g[tid + 512] + b[tid + 512];
}

// ---------- cls token fill ----------
__global__ void cls_k(const float* __restrict__ cls, float* __restrict__ x) {
    int bi = blockIdx.x, tid = threadIdx.x;
    #pragma unroll
    for (int k = 0; k < 3; ++k)
        x[(size_t)bi * 1024 * 768 + tid + k * 256] = cls[tid + k * 256];
}

// ---------- depthwise conv1d (PEG) + residual + bias ----------
__global__ __launch_bounds__(256) void peg_k(const float* __restrict__ x,
                                             const float* __restrict__ w,
                                             const float* __restrict__ pb,
                                             float* __restrict__ y) {
    int r = blockIdx.x;            // b*1024 + i
    int i = r & 1023;
    int tid = threadIdx.x;
    const float* xr = x + (size_t)r * 768;
    float* yr = y + (size_t)r * 768;
    #pragma unroll
    for (int k = 0; k < 3; ++k) {
        int d = tid + k * 256;
        float c  = xr[d];
        float lf = (i > 0)    ? xr[d - 768] : 0.f;
        float rt = (i < 1023) ? xr[d + 768] : 0.f;
        yr[d] = c + pb[d] + w[d * 3 + 0] * lf + w[d * 3 + 1] * c + w[d * 3 + 2] * rt;
    }
}

// ---------- RoPE on q and k halves of qkv, in place ----------
__global__ __launch_bounds__(384) void rope_k(float* __restrict__ qkv,
                                              const float* __restrict__ inv_freq) {
    int r = blockIdx.x;            // 0..2047
    int t = r & 1023;
    int tid = threadIdx.x;         // 0..383
    int qk  = tid / 192;           // 0=q, 1=k
    int rem = tid % 192;
    int hh  = rem / 16, p = rem % 16;
    float* base = qkv + (size_t)r * 2304 + qk * 768 + hh * 64;
    float x0 = base[2 * p], x1 = base[2 * p + 1];
    float fr = (float)t * inv_freq[p];
    float c = cosf(fr), sn = sinf(fr);
    base[2 * p]     = x0 * c - x1 * sn;
    base[2 * p + 1] = x1 * c + x0 * sn;
}

// ---------- attention: one block per (b, h, query row) ----------
__global__ __launch_bounds__(256) void attn_k(const float* __restrict__ qkv,
                                              const float* __restrict__ mask,
                                              float* __restrict__ o) {
    int bid = blockIdx.x;
    int bh = bid >> 10, t = bid & 1023;
    int bi = bh / 12, h = bh % 12;
    const float* qrow  = qkv + ((size_t)(bi * 1024 + t)) * 2304 + h * 64;
    const float* Kbase = qkv + (size_t)bi * 1024 * 2304 + 768 + h * 64;
    const float* Vbase = Kbase + 768;
    const float* mrow  = mask + ((size_t)bh * 1024 + t) * 1024;

    __shared__ float qs[64];
    __shared__ float s[1024];
    __shared__ float red[8];
    __shared__ float part[4][64];
    int tid = threadIdx.x;
    if (tid < 64) qs[tid] = qrow[tid];
    __syncthreads();

    const float scale = 0.125f;
    for (int j = tid; j < 1024; j += 256) {
        const float4* k4 = (const float4*)(Kbase + (size_t)j * 2304);
        float dot = 0.f;
        #pragma unroll
        for (int d4 = 0; d4 < 16; ++d4) {
            float4 kv = k4[d4];
            dot += qs[4 * d4] * kv.x + qs[4 * d4 + 1] * kv.y +
                   qs[4 * d4 + 2] * kv.z + qs[4 * d4 + 3] * kv.w;
        }
        s[j] = dot * scale + (1.0f - mrow[j]) * -1e9f;
    }
    __syncthreads();

    float lm = -INFINITY;
    for (int j = tid; j < 1024; j += 256) lm = fmaxf(lm, s[j]);
    #pragma unroll
    for (int off = 32; off > 0; off >>= 1) lm = fmaxf(lm, __shfl_down(lm, off));
    if ((tid & 63) == 0) red[tid >> 6] = lm;
    __syncthreads();
    float m = fmaxf(fmaxf(red[0], red[1]), fmaxf(red[2], red[3]));

    float ls = 0.f;
    for (int j = tid; j < 1024; j += 256) { float p = expf(s[j] - m); s[j] = p; ls += p; }
    #pragma unroll
    for (int off = 32; off > 0; off >>= 1) ls += __shfl_down(ls, off);
    if ((tid & 63) == 0) red[4 + (tid >> 6)] = ls;
    __syncthreads();
    float S = red[4] + red[5] + red[6] + red[7];

    int d = tid & 63, pi = tid >> 6;
    const float* Vp = Vbase + (size_t)(pi * 256) * 2304 + d;
    float acc = 0.f;
    #pragma unroll 4
    for (int j = 0; j < 256; ++j) acc += s[pi * 256 + j] * Vp[(size_t)j * 2304];
    part[pi][d] = acc;
    __syncthreads();
    if (tid < 64) {
        float rr = (part[0][tid] + part[1][tid] + part[2][tid] + part[3][tid]) / S;
        o[((size_t)(bi * 1024 + t)) * 768 + h * 64 + tid] = rr;
    }
}

// ---------- GEMM: C[M,N] = A[M,K] @ W[K,N] (+bias)(+gelu)(+residual) ----------
// 64x64 tile, BK=32, 4 waves, bf16 MFMA with f32 accumulation.
template<bool GELU>
__global__ __launch_bounds__(256) void gemm_k(const float* __restrict__ A,
                                              const float* __restrict__ W,
                                              const float* __restrict__ bias,
                                              const float* __restrict__ res,
                                              float* __restrict__ C,
                                              int M, int N, int K) {
    __shared__ alignas(16) unsigned short lA[64 * 40];
    __shared__ alignas(16) unsigned short lB[64 * 40];
    int tid = threadIdx.x;
    int n0 = blockIdx.x * 64, m0 = blockIdx.y * 64;
    int w = tid >> 6, lane = tid & 63;
    int wr = (w >> 1) * 32, wc = (w & 1) * 32;
    int l16 = lane & 15, lq = lane >> 4;
    f32x4 acc[2][2] = {};
    int arow = tid >> 2, acol = (tid & 3) * 8;
    int bkr  = tid >> 3, bnc  = (tid & 7) * 8;

    for (int k0 = 0; k0 < K; k0 += 32) {
        // stage A (f32 -> bf16)
        {
            unsigned short tmp[8];
            int gr = m0 + arow;
            if (gr < M) {
                const float* p = A + (size_t)gr * K + k0 + acol;
                float4 f0 = *(const float4*)p, f1 = *(const float4*)(p + 4);
                tmp[0] = f2bf(f0.x); tmp[1] = f2bf(f0.y); tmp[2] = f2bf(f0.z); tmp[3] = f2bf(f0.w);
                tmp[4] = f2bf(f1.x); tmp[5] = f2bf(f1.y); tmp[6] = f2bf(f1.z); tmp[7] = f2bf(f1.w);
            } else {
                #pragma unroll
                for (int j = 0; j < 8; ++j) tmp[j] = 0;
            }
            *(ushort8*)&lA[arow * 40 + acol] = *(const ushort8*)tmp;
        }
        // stage B transposed: lB[n][k]
        {
            const float* p = W + (size_t)(k0 + bkr) * N + n0 + bnc;
            float4 f0 = *(const float4*)p, f1 = *(const float4*)(p + 4);
            float ff[8] = {f0.x, f0.y, f0.z, f0.w, f1.x, f1.y, f1.z, f1.w};
            #pragma unroll
            for (int j = 0; j < 8; ++j) lB[(bnc + j) * 40 + bkr] = f2bf(ff[j]);
        }
        __syncthreads();
        bf16x8 af[2], bfr[2];
        af[0]  = *(const bf16x8*)&lA[(wr +      l16) * 40 + lq * 8];
        af[1]  = *(const bf16x8*)&lA[(wr + 16 + l16) * 40 + lq * 8];
        bfr[0] = *(const bf16x8*)&lB[(wc +      l16) * 40 + lq * 8];
        bfr[1] = *(const bf16x8*)&lB[(wc + 16 + l16) * 40 + lq * 8];
        #pragma unroll
        for (int fm = 0; fm < 2; ++fm)
            #pragma unroll
            for (int fn = 0; fn < 2; ++fn)
                acc[fm][fn] = __builtin_amdgcn_mfma_f32_16x16x32_bf16(af[fm], bfr[fn], acc[fm][fn], 0, 0, 0);
        __syncthreads();
    }

    #pragma unroll
    for (int fm = 0; fm < 2; ++fm)
        #pragma unroll
        for (int fn = 0; fn < 2; ++fn) {
            int col = n0 + wc + fn * 16 + l16;
            #pragma unroll
            for (int i = 0; i < 4; ++i) {
                int row = m0 + wr + fm * 16 + lq * 4 + i;
                if (row < M) {
                    float v = acc[fm][fn][i];
                    if (bias) v += bias[col];
                    if (GELU) v = 0.5f * v * (1.0f + erff(v * 0.70710678118f));
                    if (res)  v += res[(size_t)row * N + col];
                    C[(size_t)row * N + col] = v;
                }
            }
        }
}

// ---------- launch ----------
extern "C" void kernel_launch(void* const* d_in, const int* in_sizes, int n_in,
                              void* d_out, int out_size, void* d_ws, size_t ws_size,
                              hipStream_t stream) {
    const float* filaments = (const float*)d_in[0];
    const float* mask      = (const float*)d_in[1];
    const float* ln_p1_g   = (const float*)d_in[2];
    const float* ln_p1_b   = (const float*)d_in[3];
    const float* W_patch   = (const float*)d_in[4];
    const float* b_patch   = (const float*)d_in[5];
    const float* ln_p2_g   = (const float*)d_in[6];
    const float* ln_p2_b   = (const float*)d_in[7];
    const float* peg_w     = (const float*)d_in[8];
    const float* peg_b     = (const float*)d_in[9];
    const float* cls_token = (const float*)d_in[10];
    const float* ln_a_g    = (const float*)d_in[11];
    const float* ln_a_b    = (const float*)d_in[12];
    const float* W_qkv     = (const float*)d_in[13];
    const float* W_o       = (const float*)d_in[14];
    const float* b_o       = (const float*)d_in[15];
    const float* inv_freq  = (const float*)d_in[16];
    const float* ln_f_g    = (const float*)d_in[17];
    const float* ln_f_b    = (const float*)d_in[18];
    const float* W1        = (const float*)d_in[19];
    const float* b1        = (const float*)d_in[20];
    const float* W2        = (const float*)d_in[21];
    const float* b2        = (const float*)d_in[22];

    float* ws  = (float*)d_ws;
    float* xa  = ws;                    // 1,572,864
    float* xb  = xa + 1572864;          // 1,572,864
    float* h   = xb + 1572864;          // 1,572,864
    float* qkv = h  + 1572864;          // 4,718,592
    float* o   = qkv + 4718592;         // 1,572,864
    float* m   = qkv;                   // 6,291,456 overlay of qkv+o (safe: used after attn/o consumed)
    float* out = (float*)d_out;

    // patch embed
    ln768_k<<<2046, 256, 0, stream>>>(filaments, ln_p1_g, ln_p1_b, h, 0);
    gemm_k<false><<<dim3(12, 32), 256, 0, stream>>>(h, W_patch, b_patch, nullptr, o, 2046, 768, 768);
    ln768_k<<<2046, 256, 0, stream>>>(o, ln_p2_g, ln_p2_b, xa, 1);
    cls_k<<<2, 256, 0, stream>>>(cls_token, xa);
    peg_k<<<2048, 256, 0, stream>>>(xa, peg_w, peg_b, xb);

    float* cur = xb;   // residual stream lives here throughout
    float* nxt = xa;   // attn-residual intermediate
    for (int i = 0; i < 6; ++i) {
        ln768_k<<<2048, 256, 0, stream>>>(cur, ln_a_g + i * 768, ln_a_b + i * 768, h, 0);
        gemm_k<false><<<dim3(36, 32), 256, 0, stream>>>(h, W_qkv, nullptr, nullptr, qkv, 2048, 2304, 768);
        rope_k<<<2048, 384, 0, stream>>>(qkv, inv_freq);
        attn_k<<<24576, 256, 0, stream>>>(qkv, mask, o);
        gemm_k<false><<<dim3(12, 32), 256, 0, stream>>>(o, W_o, b_o, cur, nxt, 2048, 768, 768);
        ln768_k<<<2048, 256, 0, stream>>>(nxt, ln_f_g + i * 768, ln_f_b + i * 768, h, 0);
        gemm_k<true><<<dim3(48, 32), 256, 0, stream>>>(h, W1 + (size_t)i * 768 * 3072, b1 + i * 3072,
                                                       nullptr, m, 2048, 3072, 768);
        gemm_k<false><<<dim3(12, 32), 256, 0, stream>>>(m, W2 + (size_t)i * 3072 * 768, b2 + i * 768,
                                                        nxt, (i == 5) ? out : cur, 2048, 768, 3072);
    }
}

// Round 2
// 2042.212 us; speedup vs baseline: 5.3302x; 5.3302x over previous
//
#include <hip/hip_runtime.h>
#include <hip/hip_bf16.h>
#include <math.h>

// ---------- types ----------
typedef __attribute__((ext_vector_type(8))) short      bf16x8;
typedef __attribute__((ext_vector_type(8))) unsigned short ushort8;
typedef __attribute__((ext_vector_type(4))) float      f32x4;

__device__ __forceinline__ unsigned short f2bf(float f) {
    union { float f; unsigned u; } v; v.f = f;
    unsigned u = v.u;
    unsigned r = (u + 0x7FFFu + ((u >> 16) & 1u)) >> 16;   // RNE
    return (unsigned short)r;
}

// ---------- LayerNorm over last dim = 768 ----------
__global__ __launch_bounds__(256) void ln768_k(const float* __restrict__ in,
                                               const float* __restrict__ g,
                                               const float* __restrict__ b,
                                               float* __restrict__ out,
                                               int remap) {
    int r = blockIdx.x, tid = threadIdx.x;
    const float* x = in + (size_t)r * 768;
    float v0 = x[tid], v1 = x[tid + 256], v2 = x[tid + 512];
    __shared__ float red[4];
    float s = v0 + v1 + v2;
    #pragma unroll
    for (int off = 32; off > 0; off >>= 1) s += __shfl_down(s, off);
    if ((tid & 63) == 0) red[tid >> 6] = s;
    __syncthreads();
    float mean = (red[0] + red[1] + red[2] + red[3]) * (1.0f / 768.0f);
    float d0 = v0 - mean, d1 = v1 - mean, d2 = v2 - mean;
    float q = d0 * d0 + d1 * d1 + d2 * d2;
    __syncthreads();
    #pragma unroll
    for (int off = 32; off > 0; off >>= 1) q += __shfl_down(q, off);
    if ((tid & 63) == 0) red[tid >> 6] = q;
    __syncthreads();
    float var = (red[0] + red[1] + red[2] + red[3]) * (1.0f / 768.0f);
    float rs = rsqrtf(var + 1e-5f);
    int orow = remap ? ((r / 1023) * 1024 + 1 + (r % 1023)) : r;
    float* y = out + (size_t)orow * 768;
    y[tid]       = d0 * rs * g[tid]       + b[tid];
    y[tid + 256] = d1 * rs * g[tid + 256] + b[tid + 256];
    y[tid + 512] = d2 * rs * g[tid + 512] + b[tid + 512];
}

// ---------- cls token fill ----------
__global__ void cls_k(const float* __restrict__ cls, float* __restrict__ x) {
    int bi = blockIdx.x, tid = threadIdx.x;
    #pragma unroll
    for (int k = 0; k < 3; ++k)
        x[(size_t)bi * 1024 * 768 + tid + k * 256] = cls[tid + k * 256];
}

// ---------- depthwise conv1d (PEG) + residual + bias ----------
__global__ __launch_bounds__(256) void peg_k(const float* __restrict__ x,
                                             const float* __restrict__ w,
                                             const float* __restrict__ pb,
                                             float* __restrict__ y) {
    int r = blockIdx.x;
    int i = r & 1023;
    int tid = threadIdx.x;
    const float* xr = x + (size_t)r * 768;
    float* yr = y + (size_t)r * 768;
    #pragma unroll
    for (int k = 0; k < 3; ++k) {
        int d = tid + k * 256;
        float c  = xr[d];
        float lf = (i > 0)    ? xr[d - 768] : 0.f;
        float rt = (i < 1023) ? xr[d + 768] : 0.f;
        yr[d] = c + pb[d] + w[d * 3 + 0] * lf + w[d * 3 + 1] * c + w[d * 3 + 2] * rt;
    }
}

// ---------- RoPE on q and k halves of qkv, in place ----------
__global__ __launch_bounds__(384) void rope_k(float* __restrict__ qkv,
                                              const float* __restrict__ inv_freq) {
    int r = blockIdx.x;
    int t = r & 1023;
    int tid = threadIdx.x;
    int qk  = tid / 192;
    int rem = tid % 192;
    int hh  = rem / 16, p = rem % 16;
    float* base = qkv + (size_t)r * 2304 + qk * 768 + hh * 64;
    float x0 = base[2 * p], x1 = base[2 * p + 1];
    float fr = (float)t * inv_freq[p];
    float c = cosf(fr), sn = sinf(fr);
    base[2 * p]     = x0 * c - x1 * sn;
    base[2 * p + 1] = x1 * c + x0 * sn;
}

// ---------- MFMA flash attention ----------
// grid (16 q-tiles, 24 bh); 256 threads = 4 waves; wave w owns q rows
// q0+w*16 .. +15. KV tiles of 64 staged in LDS bf16, XOR-swizzled.
// S^T = mfma(K, Q): lane holds q = l16 (col), k = 16f + 4lq + i (row)
// -> softmax is lane-local + shfl_xor(16/32).
// P^T -> A-fragment via fixed 16-shuffle permutation; O = mfma(P, V^T).
__global__ __launch_bounds__(256) void attn_mfma_k(const float* __restrict__ qkv,
                                                   const float* __restrict__ mask,
                                                   float* __restrict__ o) {
    const int qt = blockIdx.x, bh = blockIdx.y;
    const int bi = bh / 12, h = bh % 12;
    const int tid = threadIdx.x;
    const int w = tid >> 6, lane = tid & 63;
    const int l16 = lane & 15, lq = lane >> 4;

    __shared__ unsigned short lK[64 * 64];   // K[k][d]  bf16, swizzled rows of 128B
    __shared__ unsigned short lV[64 * 64];   // V^T[d][k] bf16, swizzled

    const int q0 = qt * 64;
    const size_t tokbase = (size_t)bi * 1024;
    const int qrow = q0 + w * 16 + l16;

    // Q fragment (B-operand): lane holds Q[qrow][d = 32s + 8lq + j]
    bf16x8 qb[2];
    {
        const float* qp = qkv + (tokbase + qrow) * 2304 + h * 64;
        #pragma unroll
        for (int s = 0; s < 2; ++s) {
            const float* p = qp + s * 32 + lq * 8;
            float4 f0 = *(const float4*)p, f1 = *(const float4*)(p + 4);
            unsigned short t8[8] = { f2bf(f0.x), f2bf(f0.y), f2bf(f0.z), f2bf(f0.w),
                                     f2bf(f1.x), f2bf(f1.y), f2bf(f1.z), f2bf(f1.w) };
            qb[s] = *(const bf16x8*)t8;
        }
    }

    const float* Kg = qkv + tokbase * 2304 + 768 + h * 64;
    const float* Vg = Kg + 768;
    const float* mrow = mask + ((size_t)bh * 1024 + qrow) * 1024;

    float m_run = -1e30f, l_run = 0.f;
    f32x4 oacc[4] = {};      // O[q = 4lq+i][d = 16f + l16]

    for (int kt = 0; kt < 16; ++kt) {
        const int k0 = kt * 64;
        // ---- stage K and V^T tiles (bf16, swizzled) ----
        {
            const size_t grow = (tokbase + k0 + lane) * 2304 + h * 64 + w * 16;
            const float4* kp = (const float4*)(Kg + grow - (h * 64 + w * 16) + (h * 64 + w * 16)); // = Kg + ...
            // recompute cleanly:
            const float* krp = qkv + (tokbase + k0 + lane) * 2304 + 768 + h * 64 + w * 16;
            const float* vrp = krp + 768;
            float4 ka = *(const float4*)(krp),     kb = *(const float4*)(krp + 4);
            float4 kc = *(const float4*)(krp + 8), kd = *(const float4*)(krp + 12);
            float4 va = *(const float4*)(vrp),     vb4 = *(const float4*)(vrp + 4);
            float4 vc = *(const float4*)(vrp + 8), vd = *(const float4*)(vrp + 12);
            unsigned short kt16[16] = { f2bf(ka.x), f2bf(ka.y), f2bf(ka.z), f2bf(ka.w),
                                        f2bf(kb.x), f2bf(kb.y), f2bf(kb.z), f2bf(kb.w),
                                        f2bf(kc.x), f2bf(kc.y), f2bf(kc.z), f2bf(kc.w),
                                        f2bf(kd.x), f2bf(kd.y), f2bf(kd.z), f2bf(kd.w) };
            unsigned short vt16[16] = { f2bf(va.x), f2bf(va.y), f2bf(va.z), f2bf(va.w),
                                        f2bf(vb4.x), f2bf(vb4.y), f2bf(vb4.z), f2bf(vb4.w),
                                        f2bf(vc.x), f2bf(vc.y), f2bf(vc.z), f2bf(vc.w),
                                        f2bf(vd.x), f2bf(vd.y), f2bf(vd.z), f2bf(vd.w) };
            // K: row = lane, byte chunks (w*32 + 16c) ^ ((lane&7)<<4)
            int byA = lane * 128 + ((w * 32 +  0) ^ ((lane & 7) << 4));
            int byB = lane * 128 + ((w * 32 + 16) ^ ((lane & 7) << 4));
            *(ushort8*)((char*)lK + byA) = *(const ushort8*)&kt16[0];
            *(ushort8*)((char*)lK + byB) = *(const ushort8*)&kt16[8];
            // V^T: row = d = w*16+j, col = k = lane (scalar writes, 2-way banks = free)
            #pragma unroll
            for (int j = 0; j < 16; ++j) {
                int row = w * 16 + j;
                int by = row * 128 + ((2 * lane) ^ ((row & 7) << 4));
                *(unsigned short*)((char*)lV + by) = vt16[j];
            }
        }
        __syncthreads();

        // ---- S^T = K @ Q^T ----
        f32x4 sacc[4] = {};
        #pragma unroll
        for (int f = 0; f < 4; ++f) {
            int krow = f * 16 + l16;
            #pragma unroll
            for (int s = 0; s < 2; ++s) {
                int by = krow * 128 + (((s * 64) + lq * 16) ^ ((krow & 7) << 4));
                bf16x8 af = *(const bf16x8*)((const char*)lK + by);
                sacc[f] = __builtin_amdgcn_mfma_f32_16x16x32_bf16(af, qb[s], sacc[f], 0, 0, 0);
            }
        }

        // ---- mask + scale + online softmax (lane-local q = l16) ----
        float pv[4][4];
        float smax = -1e30f;
        #pragma unroll
        for (int f = 0; f < 4; ++f) {
            float4 mk = *(const float4*)(mrow + k0 + f * 16 + lq * 4);
            pv[f][0] = sacc[f][0] * 0.125f + (1.f - mk.x) * -1e9f;
            pv[f][1] = sacc[f][1] * 0.125f + (1.f - mk.y) * -1e9f;
            pv[f][2] = sacc[f][2] * 0.125f + (1.f - mk.z) * -1e9f;
            pv[f][3] = sacc[f][3] * 0.125f + (1.f - mk.w) * -1e9f;
            smax = fmaxf(smax, fmaxf(fmaxf(pv[f][0], pv[f][1]), fmaxf(pv[f][2], pv[f][3])));
        }
        smax = fmaxf(smax, __shfl_xor(smax, 16));
        smax = fmaxf(smax, __shfl_xor(smax, 32));
        float m_new = fmaxf(m_run, smax);
        float fac = expf(m_run - m_new);
        float lsum = 0.f;
        #pragma unroll
        for (int f = 0; f < 4; ++f) {
            #pragma unroll
            for (int i = 0; i < 4; ++i) {
                pv[f][i] = expf(pv[f][i] - m_new);
                lsum += pv[f][i];
            }
        }
        lsum += __shfl_xor(lsum, 16);
        lsum += __shfl_xor(lsum, 32);
        l_run = l_run * fac + lsum;
        m_run = m_new;

        // rescale O rows (row q_o = 4lq+i gets fac from lane l16 = 4lq+i)
        #pragma unroll
        for (int i = 0; i < 4; ++i) {
            float fi = __shfl(fac, 4 * lq + i);
            oacc[0][i] *= fi; oacc[1][i] *= fi; oacc[2][i] *= fi; oacc[3][i] *= fi;
        }

        // pack P to bf16 word pairs: wpk[f][0] = (k'=4lq+0,1), wpk[f][1] = (k'=4lq+2,3)
        unsigned wpk[4][2];
        #pragma unroll
        for (int f = 0; f < 4; ++f) {
            wpk[f][0] = (unsigned)f2bf(pv[f][0]) | ((unsigned)f2bf(pv[f][1]) << 16);
            wpk[f][1] = (unsigned)f2bf(pv[f][2]) | ((unsigned)f2bf(pv[f][3]) << 16);
        }

        // ---- O += P @ V : A-frag via shuffle permutation, B-frag from lV ----
        #pragma unroll
        for (int s = 0; s < 2; ++s) {
            unsigned aw[4];
            #pragma unroll
            for (int t = 0; t < 4; ++t) {
                int src = (2 * (lq & 1) + (t >> 1)) * 16 + l16;
                unsigned lo = __shfl(wpk[2 * s][t & 1], src);
                unsigned hi = __shfl(wpk[2 * s + 1][t & 1], src);
                aw[t] = (lq >> 1) ? hi : lo;
            }
            union { unsigned u[4]; bf16x8 v; } pa;
            pa.u[0] = aw[0]; pa.u[1] = aw[1]; pa.u[2] = aw[2]; pa.u[3] = aw[3];
            #pragma unroll
            for (int f = 0; f < 4; ++f) {
                int drow = f * 16 + l16;
                int by = drow * 128 + (((s * 64) + lq * 16) ^ ((drow & 7) << 4));
                bf16x8 vb = *(const bf16x8*)((const char*)lV + by);
                oacc[f] = __builtin_amdgcn_mfma_f32_16x16x32_bf16(pa.v, vb, oacc[f], 0, 0, 0);
            }
        }
        __syncthreads();
    }

    // ---- epilogue: divide by l, store ----
    #pragma unroll
    for (int i = 0; i < 4; ++i) {
        float li = __shfl(l_run, 4 * lq + i);
        float inv = 1.f / li;
        int row = q0 + w * 16 + 4 * lq + i;
        float* op = o + (tokbase + row) * 768 + h * 64 + l16;
        #pragma unroll
        for (int f = 0; f < 4; ++f)
            op[f * 16] = oacc[f][i] * inv;
    }
}

// ---------- GEMM: C[M,N] = A[M,K] @ W[K,N] (+bias)(+gelu)(+residual) ----------
template<bool GELU>
__global__ __launch_bounds__(256) void gemm_k(const float* __restrict__ A,
                                              const float* __restrict__ W,
                                              const float* __restrict__ bias,
                                              const float* __restrict__ res,
                                              float* __restrict__ C,
                                              int M, int N, int K) {
    __shared__ alignas(16) unsigned short lA[64 * 40];
    __shared__ alignas(16) unsigned short lB[64 * 40];
    int tid = threadIdx.x;
    int n0 = blockIdx.x * 64, m0 = blockIdx.y * 64;
    int w = tid >> 6, lane = tid & 63;
    int wr = (w >> 1) * 32, wc = (w & 1) * 32;
    int l16 = lane & 15, lq = lane >> 4;
    f32x4 acc[2][2] = {};
    int arow = tid >> 2, acol = (tid & 3) * 8;
    int bkr  = tid >> 3, bnc  = (tid & 7) * 8;

    for (int k0 = 0; k0 < K; k0 += 32) {
        {
            unsigned short tmp[8];
            int gr = m0 + arow;
            if (gr < M) {
                const float* p = A + (size_t)gr * K + k0 + acol;
                float4 f0 = *(const float4*)p, f1 = *(const float4*)(p + 4);
                tmp[0] = f2bf(f0.x); tmp[1] = f2bf(f0.y); tmp[2] = f2bf(f0.z); tmp[3] = f2bf(f0.w);
                tmp[4] = f2bf(f1.x); tmp[5] = f2bf(f1.y); tmp[6] = f2bf(f1.z); tmp[7] = f2bf(f1.w);
            } else {
                #pragma unroll
                for (int j = 0; j < 8; ++j) tmp[j] = 0;
            }
            *(ushort8*)&lA[arow * 40 + acol] = *(const ushort8*)tmp;
        }
        {
            const float* p = W + (size_t)(k0 + bkr) * N + n0 + bnc;
            float4 f0 = *(const float4*)p, f1 = *(const float4*)(p + 4);
            float ff[8] = {f0.x, f0.y, f0.z, f0.w, f1.x, f1.y, f1.z, f1.w};
            #pragma unroll
            for (int j = 0; j < 8; ++j) lB[(bnc + j) * 40 + bkr] = f2bf(ff[j]);
        }
        __syncthreads();
        bf16x8 af[2], bfr[2];
        af[0]  = *(const bf16x8*)&lA[(wr +      l16) * 40 + lq * 8];
        af[1]  = *(const bf16x8*)&lA[(wr + 16 + l16) * 40 + lq * 8];
        bfr[0] = *(const bf16x8*)&lB[(wc +      l16) * 40 + lq * 8];
        bfr[1] = *(const bf16x8*)&lB[(wc + 16 + l16) * 40 + lq * 8];
        #pragma unroll
        for (int fm = 0; fm < 2; ++fm)
            #pragma unroll
            for (int fn = 0; fn < 2; ++fn)
                acc[fm][fn] = __builtin_amdgcn_mfma_f32_16x16x32_bf16(af[fm], bfr[fn], acc[fm][fn], 0, 0, 0);
        __syncthreads();
    }

    #pragma unroll
    for (int fm = 0; fm < 2; ++fm)
        #pragma unroll
        for (int fn = 0; fn < 2; ++fn) {
            int col = n0 + wc + fn * 16 + l16;
            #pragma unroll
            for (int i = 0; i < 4; ++i) {
                int row = m0 + wr + fm * 16 + lq * 4 + i;
                if (row < M) {
                    float v = acc[fm][fn][i];
                    if (bias) v += bias[col];
                    if (GELU) v = 0.5f * v * (1.0f + erff(v * 0.70710678118f));
                    if (res)  v += res[(size_t)row * N + col];
                    C[(size_t)row * N + col] = v;
                }
            }
        }
}

// ---------- launch ----------
extern "C" void kernel_launch(void* const* d_in, const int* in_sizes, int n_in,
                              void* d_out, int out_size, void* d_ws, size_t ws_size,
                              hipStream_t stream) {
    const float* filaments = (const float*)d_in[0];
    const float* mask      = (const float*)d_in[1];
    const float* ln_p1_g   = (const float*)d_in[2];
    const float* ln_p1_b   = (const float*)d_in[3];
    const float* W_patch   = (const float*)d_in[4];
    const float* b_patch   = (const float*)d_in[5];
    const float* ln_p2_g   = (const float*)d_in[6];
    const float* ln_p2_b   = (const float*)d_in[7];
    const float* peg_w     = (const float*)d_in[8];
    const float* peg_b     = (const float*)d_in[9];
    const float* cls_token = (const float*)d_in[10];
    const float* ln_a_g    = (const float*)d_in[11];
    const float* ln_a_b    = (const float*)d_in[12];
    const float* W_qkv     = (const float*)d_in[13];
    const float* W_o       = (const float*)d_in[14];
    const float* b_o       = (const float*)d_in[15];
    const float* inv_freq  = (const float*)d_in[16];
    const float* ln_f_g    = (const float*)d_in[17];
    const float* ln_f_b    = (const float*)d_in[18];
    const float* W1        = (const float*)d_in[19];
    const float* b1        = (const float*)d_in[20];
    const float* W2        = (const float*)d_in[21];
    const float* b2        = (const float*)d_in[22];

    float* ws  = (float*)d_ws;
    float* xa  = ws;
    float* xb  = xa + 1572864;
    float* h   = xb + 1572864;
    float* qkv = h  + 1572864;
    float* o   = qkv + 4718592;
    float* m   = qkv;                // overlay of qkv+o (used after attn/o consumed)
    float* out = (float*)d_out;

    ln768_k<<<2046, 256, 0, stream>>>(filaments, ln_p1_g, ln_p1_b, h, 0);
    gemm_k<false><<<dim3(12, 32), 256, 0, stream>>>(h, W_patch, b_patch, nullptr, o, 2046, 768, 768);
    ln768_k<<<2046, 256, 0, stream>>>(o, ln_p2_g, ln_p2_b, xa, 1);
    cls_k<<<2, 256, 0, stream>>>(cls_token, xa);
    peg_k<<<2048, 256, 0, stream>>>(xa, peg_w, peg_b, xb);

    float* cur = xb;
    float* nxt = xa;
    for (int i = 0; i < 6; ++i) {
        ln768_k<<<2048, 256, 0, stream>>>(cur, ln_a_g + i * 768, ln_a_b + i * 768, h, 0);
        gemm_k<false><<<dim3(36, 32), 256, 0, stream>>>(h, W_qkv, nullptr, nullptr, qkv, 2048, 2304, 768);
        rope_k<<<2048, 384, 0, stream>>>(qkv, inv_freq);
        attn_mfma_k<<<dim3(16, 24), 256, 0, stream>>>(qkv, mask, o);
        gemm_k<false><<<dim3(12, 32), 256, 0, stream>>>(o, W_o, b_o, cur, nxt, 2048, 768, 768);
        ln768_k<<<2048, 256, 0, stream>>>(nxt, ln_f_g + i * 768, ln_f_b + i * 768, h, 0);
        gemm_k<true><<<dim3(48, 32), 256, 0, stream>>>(h, W1 + (size_t)i * 768 * 3072, b1 + i * 3072,
                                                       nullptr, m, 2048, 3072, 768);
        gemm_k<false><<<dim3(12, 32), 256, 0, stream>>>(m, W2 + (size_t)i * 3072 * 768, b2 + i * 768,
                                                        nxt, (i == 5) ? out : cur, 2048, 768, 3072);
    }
}

// Round 3
// 1426.600 us; speedup vs baseline: 7.6304x; 1.4315x over previous
//
#include <hip/hip_runtime.h>
#include <hip/hip_bf16.h>
#include <math.h>

// ---------- types ----------
typedef __attribute__((ext_vector_type(8))) short          bf16x8;
typedef __attribute__((ext_vector_type(8))) unsigned short ushort8;
typedef __attribute__((ext_vector_type(4))) float          f32x4;

__device__ __forceinline__ unsigned short f2bf(float f) {
    union { float f; unsigned u; } v; v.f = f;
    unsigned u = v.u;
    unsigned r = (u + 0x7FFFu + ((u >> 16) & 1u)) >> 16;   // RNE
    return (unsigned short)r;
}
__device__ __forceinline__ float bf2f(unsigned short h) {
    union { unsigned u; float f; } v; v.u = ((unsigned)h) << 16;
    return v.f;
}

// async global->LDS, 16B per lane (m97 pattern)
__device__ __forceinline__ void gload16(const void* g, void* l) {
    __builtin_amdgcn_global_load_lds(
        (const __attribute__((address_space(1))) void*)g,
        (__attribute__((address_space(3))) void*)l, 16, 0, 0);
}

// ---------- weight transpose-cast: in[K][N] f32 -> out[N][K] bf16 ----------
__global__ __launch_bounds__(256) void wt_cast_k(const float* __restrict__ in,
                                                 unsigned short* __restrict__ out,
                                                 int K, int N) {
    __shared__ float t[64][65];
    int n0 = blockIdx.x * 64, k0 = blockIdx.y * 64;
    int tx = threadIdx.x & 63, ty = threadIdx.x >> 6;
    #pragma unroll
    for (int p = 0; p < 16; ++p) {
        int k = ty + p * 4;
        t[k][tx] = in[(size_t)(k0 + k) * N + n0 + tx];
    }
    __syncthreads();
    #pragma unroll
    for (int p = 0; p < 16; ++p) {
        int n = ty + p * 4;
        out[(size_t)(n0 + n) * K + k0 + tx] = f2bf(t[tx][n]);
    }
}

// ---------- LayerNorm 768, f32 in -> bf16 out (pad rows >= Mvalid zeroed) ----------
__global__ __launch_bounds__(256) void ln768_bf_k(const float* __restrict__ in,
                                                  const float* __restrict__ g,
                                                  const float* __restrict__ b,
                                                  unsigned short* __restrict__ out,
                                                  int Mvalid) {
    int r = blockIdx.x, tid = threadIdx.x;
    unsigned short* y = out + (size_t)r * 768;
    if (r >= Mvalid) { y[tid] = 0; y[tid + 256] = 0; y[tid + 512] = 0; return; }
    const float* x = in + (size_t)r * 768;
    float v0 = x[tid], v1 = x[tid + 256], v2 = x[tid + 512];
    __shared__ float red[4];
    float s = v0 + v1 + v2;
    #pragma unroll
    for (int off = 32; off > 0; off >>= 1) s += __shfl_down(s, off);
    if ((tid & 63) == 0) red[tid >> 6] = s;
    __syncthreads();
    float mean = (red[0] + red[1] + red[2] + red[3]) * (1.0f / 768.0f);
    float d0 = v0 - mean, d1 = v1 - mean, d2 = v2 - mean;
    float q = d0 * d0 + d1 * d1 + d2 * d2;
    __syncthreads();
    #pragma unroll
    for (int off = 32; off > 0; off >>= 1) q += __shfl_down(q, off);
    if ((tid & 63) == 0) red[tid >> 6] = q;
    __syncthreads();
    float var = (red[0] + red[1] + red[2] + red[3]) * (1.0f / 768.0f);
    float rs = rsqrtf(var + 1e-5f);
    y[tid]       = f2bf(d0 * rs * g[tid]       + b[tid]);
    y[tid + 256] = f2bf(d1 * rs * g[tid + 256] + b[tid + 256]);
    y[tid + 512] = f2bf(d2 * rs * g[tid + 512] + b[tid + 512]);
}

// ---------- LayerNorm 768, f32 in -> f32 out (remap option for patch rows) ----------
__global__ __launch_bounds__(256) void ln768_k(const float* __restrict__ in,
                                               const float* __restrict__ g,
                                               const float* __restrict__ b,
                                               float* __restrict__ out,
                                               int remap) {
    int r = blockIdx.x, tid = threadIdx.x;
    const float* x = in + (size_t)r * 768;
    float v0 = x[tid], v1 = x[tid + 256], v2 = x[tid + 512];
    __shared__ float red[4];
    float s = v0 + v1 + v2;
    #pragma unroll
    for (int off = 32; off > 0; off >>= 1) s += __shfl_down(s, off);
    if ((tid & 63) == 0) red[tid >> 6] = s;
    __syncthreads();
    float mean = (red[0] + red[1] + red[2] + red[3]) * (1.0f / 768.0f);
    float d0 = v0 - mean, d1 = v1 - mean, d2 = v2 - mean;
    float q = d0 * d0 + d1 * d1 + d2 * d2;
    __syncthreads();
    #pragma unroll
    for (int off = 32; off > 0; off >>= 1) q += __shfl_down(q, off);
    if ((tid & 63) == 0) red[tid >> 6] = q;
    __syncthreads();
    float var = (red[0] + red[1] + red[2] + red[3]) * (1.0f / 768.0f);
    float rs = rsqrtf(var + 1e-5f);
    int orow = remap ? ((r / 1023) * 1024 + 1 + (r % 1023)) : r;
    float* y = out + (size_t)orow * 768;
    y[tid]       = d0 * rs * g[tid]       + b[tid];
    y[tid + 256] = d1 * rs * g[tid + 256] + b[tid + 256];
    y[tid + 512] = d2 * rs * g[tid + 512] + b[tid + 512];
}

// ---------- cls token fill ----------
__global__ void cls_k(const float* __restrict__ cls, float* __restrict__ x) {
    int bi = blockIdx.x, tid = threadIdx.x;
    #pragma unroll
    for (int k = 0; k < 3; ++k)
        x[(size_t)bi * 1024 * 768 + tid + k * 256] = cls[tid + k * 256];
}

// ---------- depthwise conv1d (PEG) + residual + bias ----------
__global__ __launch_bounds__(256) void peg_k(const float* __restrict__ x,
                                             const float* __restrict__ w,
                                             const float* __restrict__ pb,
                                             float* __restrict__ y) {
    int r = blockIdx.x;
    int i = r & 1023;
    int tid = threadIdx.x;
    const float* xr = x + (size_t)r * 768;
    float* yr = y + (size_t)r * 768;
    #pragma unroll
    for (int k = 0; k < 3; ++k) {
        int d = tid + k * 256;
        float c  = xr[d];
        float lf = (i > 0)    ? xr[d - 768] : 0.f;
        float rt = (i < 1023) ? xr[d + 768] : 0.f;
        yr[d] = c + pb[d] + w[d * 3 + 0] * lf + w[d * 3 + 1] * c + w[d * 3 + 2] * rt;
    }
}

// ---------- RoPE on q and k halves of bf16 qkv, in place ----------
__global__ __launch_bounds__(384) void rope_bf_k(unsigned short* __restrict__ qkv,
                                                 const float* __restrict__ inv_freq) {
    int r = blockIdx.x;
    int t = r & 1023;
    int tid = threadIdx.x;
    int qk  = tid / 192;
    int rem = tid % 192;
    int hh  = rem / 16, p = rem % 16;
    unsigned short* base = qkv + (size_t)r * 2304 + qk * 768 + hh * 64;
    float x0 = bf2f(base[2 * p]), x1 = bf2f(base[2 * p + 1]);
    float fr = (float)t * inv_freq[p];
    float c = cosf(fr), sn = sinf(fr);
    base[2 * p]     = f2bf(x0 * c - x1 * sn);
    base[2 * p + 1] = f2bf(x1 * c + x0 * sn);
}

// ---------- MFMA flash attention (bf16 qkv in, bf16 o out) ----------
__global__ __launch_bounds__(256) void attn_mfma_k(const unsigned short* __restrict__ qkv,
                                                   const float* __restrict__ mask,
                                                   unsigned short* __restrict__ o) {
    const int qt = blockIdx.x, bh = blockIdx.y;
    const int bi = bh / 12, h = bh % 12;
    const int tid = threadIdx.x;
    const int w = tid >> 6, lane = tid & 63;
    const int l16 = lane & 15, lq = lane >> 4;

    __shared__ unsigned short lK[64 * 64];   // K[k][d]  bf16, XOR-swizzled 128B rows
    __shared__ unsigned short lV[64 * 64];   // V^T[d][k] bf16, XOR-swizzled

    const int q0 = qt * 64;
    const size_t tokbase = (size_t)bi * 1024;
    const int qrow = q0 + w * 16 + l16;

    // Q fragment (B-operand): lane holds Q[qrow][d = 32s + 8lq + j]
    bf16x8 qb[2];
    {
        const unsigned short* qp = qkv + (tokbase + qrow) * 2304 + h * 64;
        qb[0] = *(const bf16x8*)(qp + lq * 8);
        qb[1] = *(const bf16x8*)(qp + 32 + lq * 8);
    }

    const float* mrow = mask + ((size_t)bh * 1024 + qrow) * 1024;

    float m_run = -1e30f, l_run = 0.f;
    f32x4 oacc[4] = {};      // O[q = 4lq+i][d = 16f + l16]

    for (int kt = 0; kt < 16; ++kt) {
        const int k0 = kt * 64;
        // ---- stage K and V^T tiles ----
        {
            const unsigned short* krp = qkv + (tokbase + k0 + lane) * 2304 + 768 + h * 64 + w * 16;
            const unsigned short* vrp = krp + 768;
            ushort8 kA = *(const ushort8*)krp, kB = *(const ushort8*)(krp + 8);
            ushort8 vA = *(const ushort8*)vrp, vB = *(const ushort8*)(vrp + 8);
            int byA = lane * 128 + ((w * 32 +  0) ^ ((lane & 7) << 4));
            int byB = lane * 128 + ((w * 32 + 16) ^ ((lane & 7) << 4));
            *(ushort8*)((char*)lK + byA) = kA;
            *(ushort8*)((char*)lK + byB) = kB;
            #pragma unroll
            for (int j = 0; j < 16; ++j) {
                int row = w * 16 + j;
                int by = row * 128 + ((2 * lane) ^ ((row & 7) << 4));
                *(unsigned short*)((char*)lV + by) = (j < 8) ? (unsigned short)vA[j] : (unsigned short)vB[j - 8];
            }
        }
        __syncthreads();

        // ---- S^T = K @ Q^T ----
        f32x4 sacc[4] = {};
        #pragma unroll
        for (int f = 0; f < 4; ++f) {
            int krow = f * 16 + l16;
            #pragma unroll
            for (int s = 0; s < 2; ++s) {
                int by = krow * 128 + (((s * 64) + lq * 16) ^ ((krow & 7) << 4));
                bf16x8 af = *(const bf16x8*)((const char*)lK + by);
                sacc[f] = __builtin_amdgcn_mfma_f32_16x16x32_bf16(af, qb[s], sacc[f], 0, 0, 0);
            }
        }

        // ---- mask + scale + online softmax (lane-local q = l16) ----
        float pv[4][4];
        float smax = -1e30f;
        #pragma unroll
        for (int f = 0; f < 4; ++f) {
            float4 mk = *(const float4*)(mrow + k0 + f * 16 + lq * 4);
            pv[f][0] = sacc[f][0] * 0.125f + (1.f - mk.x) * -1e9f;
            pv[f][1] = sacc[f][1] * 0.125f + (1.f - mk.y) * -1e9f;
            pv[f][2] = sacc[f][2] * 0.125f + (1.f - mk.z) * -1e9f;
            pv[f][3] = sacc[f][3] * 0.125f + (1.f - mk.w) * -1e9f;
            smax = fmaxf(smax, fmaxf(fmaxf(pv[f][0], pv[f][1]), fmaxf(pv[f][2], pv[f][3])));
        }
        smax = fmaxf(smax, __shfl_xor(smax, 16));
        smax = fmaxf(smax, __shfl_xor(smax, 32));
        float m_new = fmaxf(m_run, smax);
        float fac = expf(m_run - m_new);
        float lsum = 0.f;
        #pragma unroll
        for (int f = 0; f < 4; ++f) {
            #pragma unroll
            for (int i = 0; i < 4; ++i) {
                pv[f][i] = expf(pv[f][i] - m_new);
                lsum += pv[f][i];
            }
        }
        lsum += __shfl_xor(lsum, 16);
        lsum += __shfl_xor(lsum, 32);
        l_run = l_run * fac + lsum;
        m_run = m_new;

        #pragma unroll
        for (int i = 0; i < 4; ++i) {
            float fi = __shfl(fac, 4 * lq + i);
            oacc[0][i] *= fi; oacc[1][i] *= fi; oacc[2][i] *= fi; oacc[3][i] *= fi;
        }

        unsigned wpk[4][2];
        #pragma unroll
        for (int f = 0; f < 4; ++f) {
            wpk[f][0] = (unsigned)f2bf(pv[f][0]) | ((unsigned)f2bf(pv[f][1]) << 16);
            wpk[f][1] = (unsigned)f2bf(pv[f][2]) | ((unsigned)f2bf(pv[f][3]) << 16);
        }

        // ---- O += P @ V ----
        #pragma unroll
        for (int s = 0; s < 2; ++s) {
            unsigned aw[4];
            #pragma unroll
            for (int t = 0; t < 4; ++t) {
                int src = (2 * (lq & 1) + (t >> 1)) * 16 + l16;
                unsigned lo = __shfl(wpk[2 * s][t & 1], src);
                unsigned hi = __shfl(wpk[2 * s + 1][t & 1], src);
                aw[t] = (lq >> 1) ? hi : lo;
            }
            union { unsigned u[4]; bf16x8 v; } pa;
            pa.u[0] = aw[0]; pa.u[1] = aw[1]; pa.u[2] = aw[2]; pa.u[3] = aw[3];
            #pragma unroll
            for (int f = 0; f < 4; ++f) {
                int drow = f * 16 + l16;
                int by = drow * 128 + (((s * 64) + lq * 16) ^ ((drow & 7) << 4));
                bf16x8 vb = *(const bf16x8*)((const char*)lV + by);
                oacc[f] = __builtin_amdgcn_mfma_f32_16x16x32_bf16(pa.v, vb, oacc[f], 0, 0, 0);
            }
        }
        __syncthreads();
    }

    #pragma unroll
    for (int i = 0; i < 4; ++i) {
        float li = __shfl(l_run, 4 * lq + i);
        float inv = 1.f / li;
        int row = q0 + w * 16 + 4 * lq + i;
        unsigned short* op = o + (tokbase + row) * 768 + h * 64 + l16;
        #pragma unroll
        for (int f = 0; f < 4; ++f)
            op[f * 16] = f2bf(oacc[f][i] * inv);
    }
}

// ---------- GEMM (m97 structure): C[M,N] = A[M,K] @ Bt[N,K]^T ----------
// BM=128, BK=32, 4 waves (2x2), global_load_lds 16B staging, linear LDS.
template<int BN, bool GELU, bool OBF16>
__global__ __launch_bounds__(256) void gemm_bt_k(const unsigned short* __restrict__ A,
                                                 const unsigned short* __restrict__ Bt,
                                                 const float* __restrict__ bias,
                                                 const float* __restrict__ res,
                                                 void* __restrict__ Cv,
                                                 int M, int N, int K) {
    constexpr int FN = BN / 32;                 // B frags per wave
    __shared__ unsigned short lA[128 * 32];
    __shared__ unsigned short lB[BN * 32];
    int tid = threadIdx.x;
    int m0 = blockIdx.y * 128, n0 = blockIdx.x * BN;
    int w = tid >> 6, lane = tid & 63;
    int l16 = lane & 15, lq = lane >> 4;
    int wrow = (w >> 1) * 64, wcol = (w & 1) * (BN / 2);

    f32x4 acc[4][FN] = {};

    for (int k0 = 0; k0 < K; k0 += 32) {
        #pragma unroll
        for (int i = 0; i < 2; ++i) {           // A tile: 512 chunks
            int ch = tid + i * 256;
            int r = ch >> 2, c = ch & 3;
            gload16(A + (size_t)(m0 + r) * K + k0 + c * 8, lA + ch * 8);
        }
        #pragma unroll
        for (int i = 0; i < BN / 64; ++i) {     // B tile: BN*4 chunks
            int ch = tid + i * 256;
            int r = ch >> 2, c = ch & 3;
            gload16(Bt + (size_t)(n0 + r) * K + k0 + c * 8, lB + ch * 8);
        }
        __syncthreads();

        bf16x8 af[4], bfv[FN];
        #pragma unroll
        for (int fm = 0; fm < 4; ++fm)
            af[fm] = *(const bf16x8*)&lA[(wrow + fm * 16 + l16) * 32 + lq * 8];
        #pragma unroll
        for (int fn = 0; fn < FN; ++fn)
            bfv[fn] = *(const bf16x8*)&lB[(wcol + fn * 16 + l16) * 32 + lq * 8];
        #pragma unroll
        for (int fm = 0; fm < 4; ++fm)
            #pragma unroll
            for (int fn = 0; fn < FN; ++fn)
                acc[fm][fn] = __builtin_amdgcn_mfma_f32_16x16x32_bf16(af[fm], bfv[fn], acc[fm][fn], 0, 0, 0);
        __syncthreads();
    }

    float* Cf = (float*)Cv;
    unsigned short* Cb = (unsigned short*)Cv;
    #pragma unroll
    for (int fm = 0; fm < 4; ++fm)
        #pragma unroll
        for (int fn = 0; fn < FN; ++fn) {
            int col = n0 + wcol + fn * 16 + l16;
            float bv = bias ? bias[col] : 0.f;
            #pragma unroll
            for (int i = 0; i < 4; ++i) {
                int row = m0 + wrow + fm * 16 + 4 * lq + i;
                if (row < M) {
                    float v = acc[fm][fn][i] + bv;
                    if (GELU) v = 0.5f * v * (1.0f + erff(v * 0.70710678118f));
                    if (res)  v += res[(size_t)row * N + col];
                    if (OBF16) Cb[(size_t)row * N + col] = f2bf(v);
                    else       Cf[(size_t)row * N + col] = v;
                }
            }
        }
}

// ---------- launch ----------
extern "C" void kernel_launch(void* const* d_in, const int* in_sizes, int n_in,
                              void* d_out, int out_size, void* d_ws, size_t ws_size,
                              hipStream_t stream) {
    const float* filaments = (const float*)d_in[0];
    const float* mask      = (const float*)d_in[1];
    const float* ln_p1_g   = (const float*)d_in[2];
    const float* ln_p1_b   = (const float*)d_in[3];
    const float* W_patch   = (const float*)d_in[4];
    const float* b_patch   = (const float*)d_in[5];
    const float* ln_p2_g   = (const float*)d_in[6];
    const float* ln_p2_b   = (const float*)d_in[7];
    const float* peg_w     = (const float*)d_in[8];
    const float* peg_b     = (const float*)d_in[9];
    const float* cls_token = (const float*)d_in[10];
    const float* ln_a_g    = (const float*)d_in[11];
    const float* ln_a_b    = (const float*)d_in[12];
    const float* W_qkv     = (const float*)d_in[13];
    const float* W_o       = (const float*)d_in[14];
    const float* b_o       = (const float*)d_in[15];
    const float* inv_freq  = (const float*)d_in[16];
    const float* ln_f_g    = (const float*)d_in[17];
    const float* ln_f_b    = (const float*)d_in[18];
    const float* W1        = (const float*)d_in[19];
    const float* b1        = (const float*)d_in[20];
    const float* W2        = (const float*)d_in[21];
    const float* b2        = (const float*)d_in[22];

    // ---- workspace layout (38.9 MB) ----
    char* p = (char*)d_ws;
    float* xa            = (float*)p;          p += 2048 * 768 * 4;
    float* xb            = (float*)p;          p += 2048 * 768 * 4;
    unsigned short* h_bf = (unsigned short*)p; p += 2048 * 768 * 2;
    unsigned short* qkv  = (unsigned short*)p; p += 2048 * 3072 * 2;   // qkv (9.4MB) / m_bf (12.6MB) overlay
    unsigned short* wbuf = (unsigned short*)p; p += 3072 * 768 * 2;    // per-layer W1t/W2t
    unsigned short* wqt  = (unsigned short*)p; p += 2304 * 768 * 2;
    unsigned short* wot  = (unsigned short*)p; p += 768 * 768 * 2;
    unsigned short* wpt  = (unsigned short*)p; p += 768 * 768 * 2;
    unsigned short* m_bf = qkv;
    float* tmp = (float*)qkv;                  // patch GEMM f32 out (6.3MB, fits)
    float* out = (float*)d_out;

    // ---- one-time weight casts ----
    wt_cast_k<<<dim3(12, 12), 256, 0, stream>>>(W_patch, wpt, 768, 768);
    wt_cast_k<<<dim3(36, 12), 256, 0, stream>>>(W_qkv,  wqt, 768, 2304);
    wt_cast_k<<<dim3(12, 12), 256, 0, stream>>>(W_o,    wot, 768, 768);

    // ---- patch embed ----
    ln768_bf_k<<<2048, 256, 0, stream>>>(filaments, ln_p1_g, ln_p1_b, h_bf, 2046);
    gemm_bt_k<64, false, false><<<dim3(12, 16), 256, 0, stream>>>(h_bf, wpt, b_patch, nullptr, tmp, 2046, 768, 768);
    ln768_k<<<2046, 256, 0, stream>>>(tmp, ln_p2_g, ln_p2_b, xa, 1);
    cls_k<<<2, 256, 0, stream>>>(cls_token, xa);
    peg_k<<<2048, 256, 0, stream>>>(xa, peg_w, peg_b, xb);

    float* cur = xb;
    float* nxt = xa;
    for (int i = 0; i < 6; ++i) {
        ln768_bf_k<<<2048, 256, 0, stream>>>(cur, ln_a_g + i * 768, ln_a_b + i * 768, h_bf, 2048);
        gemm_bt_k<128, false, true><<<dim3(18, 16), 256, 0, stream>>>(h_bf, wqt, nullptr, nullptr, qkv, 2048, 2304, 768);
        rope_bf_k<<<2048, 384, 0, stream>>>(qkv, inv_freq);
        attn_mfma_k<<<dim3(16, 24), 256, 0, stream>>>(qkv, mask, h_bf);
        gemm_bt_k<64, false, false><<<dim3(12, 16), 256, 0, stream>>>(h_bf, wot, b_o, cur, nxt, 2048, 768, 768);
        ln768_bf_k<<<2048, 256, 0, stream>>>(nxt, ln_f_g + i * 768, ln_f_b + i * 768, h_bf, 2048);
        wt_cast_k<<<dim3(48, 12), 256, 0, stream>>>(W1 + (size_t)i * 768 * 3072, wbuf, 768, 3072);
        gemm_bt_k<128, true, true><<<dim3(24, 16), 256, 0, stream>>>(h_bf, wbuf, b1 + i * 3072, nullptr, m_bf, 2048, 3072, 768);
        wt_cast_k<<<dim3(12, 48), 256, 0, stream>>>(W2 + (size_t)i * 3072 * 768, wbuf, 3072, 768);
        gemm_bt_k<64, false, false><<<dim3(12, 16), 256, 0, stream>>>(m_bf, wbuf, b2 + i * 768, nxt, (i == 5) ? out : cur, 2048, 768, 3072);
    }
}

// Round 4
// 1343.513 us; speedup vs baseline: 8.1022x; 1.0618x over previous
//
#include <hip/hip_runtime.h>
#include <hip/hip_bf16.h>
#include <math.h>

// ---------- types ----------
typedef __attribute__((ext_vector_type(8))) short          bf16x8;
typedef __attribute__((ext_vector_type(8))) unsigned short ushort8;
typedef __attribute__((ext_vector_type(4))) float          f32x4;

__device__ __forceinline__ unsigned short f2bf(float f) {
    union { float f; unsigned u; } v; v.f = f;
    unsigned u = v.u;
    unsigned r = (u + 0x7FFFu + ((u >> 16) & 1u)) >> 16;   // RNE
    return (unsigned short)r;
}
__device__ __forceinline__ float bf2f(unsigned short h) {
    union { unsigned u; float f; } v; v.u = ((unsigned)h) << 16;
    return v.f;
}

// async global->LDS, 16B per lane (m97 pattern)
__device__ __forceinline__ void gload16(const void* g, void* l) {
    __builtin_amdgcn_global_load_lds(
        (const __attribute__((address_space(1))) void*)g,
        (__attribute__((address_space(3))) void*)l, 16, 0, 0);
}

// ---------- weight transpose-cast: in[K][N] f32 -> out[N][K] bf16 ----------
__global__ __launch_bounds__(256) void wt_cast_k(const float* __restrict__ in,
                                                 unsigned short* __restrict__ out,
                                                 int K, int N) {
    __shared__ float t[64][65];
    int n0 = blockIdx.x * 64, k0 = blockIdx.y * 64;
    int tx = threadIdx.x & 63, ty = threadIdx.x >> 6;
    #pragma unroll
    for (int p = 0; p < 16; ++p) {
        int k = ty + p * 4;
        t[k][tx] = in[(size_t)(k0 + k) * N + n0 + tx];
    }
    __syncthreads();
    #pragma unroll
    for (int p = 0; p < 16; ++p) {
        int n = ty + p * 4;
        out[(size_t)(n0 + n) * K + k0 + tx] = f2bf(t[tx][n]);
    }
}

// ---------- mask triviality flags: 1 if 64x64 block of mask is all ones ----------
__global__ __launch_bounds__(256) void mask_flags_k(const float* __restrict__ mask,
                                                    unsigned char* __restrict__ flags) {
    int idx = blockIdx.x;                    // (bh*16 + qt)*16 + kt
    int tid = threadIdx.x;
    int kt = idx & 15, qt = (idx >> 4) & 15, bh = idx >> 8;
    int r = tid >> 2, cc = (tid & 3) * 16;
    const float* prow = mask + ((size_t)bh * 1024 + (size_t)qt * 64 + r) * 1024 + kt * 64 + cc;
    int bad = 0;
    #pragma unroll
    for (int j = 0; j < 4; ++j) {
        float4 v = *(const float4*)(prow + j * 4);
        bad |= (v.x != 1.f) || (v.y != 1.f) || (v.z != 1.f) || (v.w != 1.f);
    }
    __shared__ int sb[4];
    unsigned long long anyb = __ballot(bad != 0);
    if ((tid & 63) == 0) sb[tid >> 6] = (anyb != 0ull) ? 1 : 0;
    __syncthreads();
    if (tid == 0) flags[idx] = (unsigned char)(!(sb[0] | sb[1] | sb[2] | sb[3]));
}

// ---------- LayerNorm 768, f32 in -> bf16 out (pad rows >= Mvalid zeroed) ----------
__global__ __launch_bounds__(256) void ln768_bf_k(const float* __restrict__ in,
                                                  const float* __restrict__ g,
                                                  const float* __restrict__ b,
                                                  unsigned short* __restrict__ out,
                                                  int Mvalid) {
    int r = blockIdx.x, tid = threadIdx.x;
    unsigned short* y = out + (size_t)r * 768;
    if (r >= Mvalid) { y[tid] = 0; y[tid + 256] = 0; y[tid + 512] = 0; return; }
    const float* x = in + (size_t)r * 768;
    float v0 = x[tid], v1 = x[tid + 256], v2 = x[tid + 512];
    __shared__ float red[4];
    float s = v0 + v1 + v2;
    #pragma unroll
    for (int off = 32; off > 0; off >>= 1) s += __shfl_down(s, off);
    if ((tid & 63) == 0) red[tid >> 6] = s;
    __syncthreads();
    float mean = (red[0] + red[1] + red[2] + red[3]) * (1.0f / 768.0f);
    float d0 = v0 - mean, d1 = v1 - mean, d2 = v2 - mean;
    float q = d0 * d0 + d1 * d1 + d2 * d2;
    __syncthreads();
    #pragma unroll
    for (int off = 32; off > 0; off >>= 1) q += __shfl_down(q, off);
    if ((tid & 63) == 0) red[tid >> 6] = q;
    __syncthreads();
    float var = (red[0] + red[1] + red[2] + red[3]) * (1.0f / 768.0f);
    float rs = rsqrtf(var + 1e-5f);
    y[tid]       = f2bf(d0 * rs * g[tid]       + b[tid]);
    y[tid + 256] = f2bf(d1 * rs * g[tid + 256] + b[tid + 256]);
    y[tid + 512] = f2bf(d2 * rs * g[tid + 512] + b[tid + 512]);
}

// ---------- LayerNorm 768, f32 in -> f32 out (remap option for patch rows) ----------
__global__ __launch_bounds__(256) void ln768_k(const float* __restrict__ in,
                                               const float* __restrict__ g,
                                               const float* __restrict__ b,
                                               float* __restrict__ out,
                                               int remap) {
    int r = blockIdx.x, tid = threadIdx.x;
    const float* x = in + (size_t)r * 768;
    float v0 = x[tid], v1 = x[tid + 256], v2 = x[tid + 512];
    __shared__ float red[4];
    float s = v0 + v1 + v2;
    #pragma unroll
    for (int off = 32; off > 0; off >>= 1) s += __shfl_down(s, off);
    if ((tid & 63) == 0) red[tid >> 6] = s;
    __syncthreads();
    float mean = (red[0] + red[1] + red[2] + red[3]) * (1.0f / 768.0f);
    float d0 = v0 - mean, d1 = v1 - mean, d2 = v2 - mean;
    float q = d0 * d0 + d1 * d1 + d2 * d2;
    __syncthreads();
    #pragma unroll
    for (int off = 32; off > 0; off >>= 1) q += __shfl_down(q, off);
    if ((tid & 63) == 0) red[tid >> 6] = q;
    __syncthreads();
    float var = (red[0] + red[1] + red[2] + red[3]) * (1.0f / 768.0f);
    float rs = rsqrtf(var + 1e-5f);
    int orow = remap ? ((r / 1023) * 1024 + 1 + (r % 1023)) : r;
    float* y = out + (size_t)orow * 768;
    y[tid]       = d0 * rs * g[tid]       + b[tid];
    y[tid + 256] = d1 * rs * g[tid + 256] + b[tid + 256];
    y[tid + 512] = d2 * rs * g[tid + 512] + b[tid + 512];
}

// ---------- cls token fill ----------
__global__ void cls_k(const float* __restrict__ cls, float* __restrict__ x) {
    int bi = blockIdx.x, tid = threadIdx.x;
    #pragma unroll
    for (int k = 0; k < 3; ++k)
        x[(size_t)bi * 1024 * 768 + tid + k * 256] = cls[tid + k * 256];
}

// ---------- depthwise conv1d (PEG) + residual + bias ----------
__global__ __launch_bounds__(256) void peg_k(const float* __restrict__ x,
                                             const float* __restrict__ w,
                                             const float* __restrict__ pb,
                                             float* __restrict__ y) {
    int r = blockIdx.x;
    int i = r & 1023;
    int tid = threadIdx.x;
    const float* xr = x + (size_t)r * 768;
    float* yr = y + (size_t)r * 768;
    #pragma unroll
    for (int k = 0; k < 3; ++k) {
        int d = tid + k * 256;
        float c  = xr[d];
        float lf = (i > 0)    ? xr[d - 768] : 0.f;
        float rt = (i < 1023) ? xr[d + 768] : 0.f;
        yr[d] = c + pb[d] + w[d * 3 + 0] * lf + w[d * 3 + 1] * c + w[d * 3 + 2] * rt;
    }
}

// ---------- RoPE on q and k halves of bf16 qkv, in place ----------
__global__ __launch_bounds__(384) void rope_bf_k(unsigned short* __restrict__ qkv,
                                                 const float* __restrict__ inv_freq) {
    int r = blockIdx.x;
    int t = r & 1023;
    int tid = threadIdx.x;
    int qk  = tid / 192;
    int rem = tid % 192;
    int hh  = rem / 16, p = rem % 16;
    unsigned short* base = qkv + (size_t)r * 2304 + qk * 768 + hh * 64;
    float x0 = bf2f(base[2 * p]), x1 = bf2f(base[2 * p + 1]);
    float fr = (float)t * inv_freq[p];
    float c = cosf(fr), sn = sinf(fr);
    base[2 * p]     = f2bf(x0 * c - x1 * sn);
    base[2 * p + 1] = f2bf(x1 * c + x0 * sn);
}

// ---------- MFMA flash attention (bf16 qkv in, bf16 o out) ----------
__global__ __launch_bounds__(256) void attn_mfma_k(const unsigned short* __restrict__ qkv,
                                                   const float* __restrict__ mask,
                                                   const unsigned char* __restrict__ flags,
                                                   unsigned short* __restrict__ o) {
    const int qt = blockIdx.x, bh = blockIdx.y;
    const int bi = bh / 12, h = bh % 12;
    const int tid = threadIdx.x;
    const int w = tid >> 6, lane = tid & 63;
    const int l16 = lane & 15, lq = lane >> 4;

    __shared__ unsigned short lK[64 * 64];   // K[k][d]  bf16, XOR-swizzled 128B rows
    __shared__ unsigned short lV[64 * 64];   // V^T[d][k] bf16, XOR-swizzled

    const int q0 = qt * 64;
    const size_t tokbase = (size_t)bi * 1024;
    const int qrow = q0 + w * 16 + l16;

    // Q fragment (B-operand): lane holds Q[qrow][d = 32s + 8lq + j]
    bf16x8 qb[2];
    {
        const unsigned short* qp = qkv + (tokbase + qrow) * 2304 + h * 64;
        qb[0] = *(const bf16x8*)(qp + lq * 8);
        qb[1] = *(const bf16x8*)(qp + 32 + lq * 8);
    }

    const float* mrow = mask + ((size_t)bh * 1024 + qrow) * 1024;
    const unsigned char* fl = flags + ((size_t)bh * 16 + qt) * 16;

    float m_run = -1e30f, l_run = 0.f;
    f32x4 oacc[4] = {};      // O[q = 4lq+i][d = 16f + l16]

    for (int kt = 0; kt < 16; ++kt) {
        const int k0 = kt * 64;
        const bool triv = fl[kt] != 0;
        // ---- stage K and V^T tiles ----
        {
            const unsigned short* krp = qkv + (tokbase + k0 + lane) * 2304 + 768 + h * 64 + w * 16;
            const unsigned short* vrp = krp + 768;
            ushort8 kA = *(const ushort8*)krp, kB = *(const ushort8*)(krp + 8);
            ushort8 vA = *(const ushort8*)vrp, vB = *(const ushort8*)(vrp + 8);
            int byA = lane * 128 + ((w * 32 +  0) ^ ((lane & 7) << 4));
            int byB = lane * 128 + ((w * 32 + 16) ^ ((lane & 7) << 4));
            *(ushort8*)((char*)lK + byA) = kA;
            *(ushort8*)((char*)lK + byB) = kB;
            #pragma unroll
            for (int j = 0; j < 16; ++j) {
                int row = w * 16 + j;
                int by = row * 128 + ((2 * lane) ^ ((row & 7) << 4));
                *(unsigned short*)((char*)lV + by) = (j < 8) ? (unsigned short)vA[j] : (unsigned short)vB[j - 8];
            }
        }
        __syncthreads();

        // ---- S^T = K @ Q^T ----
        f32x4 sacc[4] = {};
        #pragma unroll
        for (int f = 0; f < 4; ++f) {
            int krow = f * 16 + l16;
            #pragma unroll
            for (int s = 0; s < 2; ++s) {
                int by = krow * 128 + (((s * 64) + lq * 16) ^ ((krow & 7) << 4));
                bf16x8 af = *(const bf16x8*)((const char*)lK + by);
                sacc[f] = __builtin_amdgcn_mfma_f32_16x16x32_bf16(af, qb[s], sacc[f], 0, 0, 0);
            }
        }

        // ---- mask + scale + online softmax (lane-local q = l16) ----
        float pv[4][4];
        float smax = -1e30f;
        if (triv) {
            #pragma unroll
            for (int f = 0; f < 4; ++f) {
                pv[f][0] = sacc[f][0] * 0.125f;
                pv[f][1] = sacc[f][1] * 0.125f;
                pv[f][2] = sacc[f][2] * 0.125f;
                pv[f][3] = sacc[f][3] * 0.125f;
                smax = fmaxf(smax, fmaxf(fmaxf(pv[f][0], pv[f][1]), fmaxf(pv[f][2], pv[f][3])));
            }
        } else {
            #pragma unroll
            for (int f = 0; f < 4; ++f) {
                float4 mk = *(const float4*)(mrow + k0 + f * 16 + lq * 4);
                pv[f][0] = sacc[f][0] * 0.125f + (1.f - mk.x) * -1e9f;
                pv[f][1] = sacc[f][1] * 0.125f + (1.f - mk.y) * -1e9f;
                pv[f][2] = sacc[f][2] * 0.125f + (1.f - mk.z) * -1e9f;
                pv[f][3] = sacc[f][3] * 0.125f + (1.f - mk.w) * -1e9f;
                smax = fmaxf(smax, fmaxf(fmaxf(pv[f][0], pv[f][1]), fmaxf(pv[f][2], pv[f][3])));
            }
        }
        smax = fmaxf(smax, __shfl_xor(smax, 16));
        smax = fmaxf(smax, __shfl_xor(smax, 32));
        float m_new = fmaxf(m_run, smax);
        float fac = expf(m_run - m_new);
        float lsum = 0.f;
        #pragma unroll
        for (int f = 0; f < 4; ++f) {
            #pragma unroll
            for (int i = 0; i < 4; ++i) {
                pv[f][i] = expf(pv[f][i] - m_new);
                lsum += pv[f][i];
            }
        }
        lsum += __shfl_xor(lsum, 16);
        lsum += __shfl_xor(lsum, 32);
        l_run = l_run * fac + lsum;
        m_run = m_new;

        #pragma unroll
        for (int i = 0; i < 4; ++i) {
            float fi = __shfl(fac, 4 * lq + i);
            oacc[0][i] *= fi; oacc[1][i] *= fi; oacc[2][i] *= fi; oacc[3][i] *= fi;
        }

        unsigned wpk[4][2];
        #pragma unroll
        for (int f = 0; f < 4; ++f) {
            wpk[f][0] = (unsigned)f2bf(pv[f][0]) | ((unsigned)f2bf(pv[f][1]) << 16);
            wpk[f][1] = (unsigned)f2bf(pv[f][2]) | ((unsigned)f2bf(pv[f][3]) << 16);
        }

        // ---- O += P @ V ----
        #pragma unroll
        for (int s = 0; s < 2; ++s) {
            unsigned aw[4];
            #pragma unroll
            for (int t = 0; t < 4; ++t) {
                int src = (2 * (lq & 1) + (t >> 1)) * 16 + l16;
                unsigned lo = __shfl(wpk[2 * s][t & 1], src);
                unsigned hi = __shfl(wpk[2 * s + 1][t & 1], src);
                aw[t] = (lq >> 1) ? hi : lo;
            }
            union { unsigned u[4]; bf16x8 v; } pa;
            pa.u[0] = aw[0]; pa.u[1] = aw[1]; pa.u[2] = aw[2]; pa.u[3] = aw[3];
            #pragma unroll
            for (int f = 0; f < 4; ++f) {
                int drow = f * 16 + l16;
                int by = drow * 128 + (((s * 64) + lq * 16) ^ ((drow & 7) << 4));
                bf16x8 vb = *(const bf16x8*)((const char*)lV + by);
                oacc[f] = __builtin_amdgcn_mfma_f32_16x16x32_bf16(pa.v, vb, oacc[f], 0, 0, 0);
            }
        }
        __syncthreads();
    }

    #pragma unroll
    for (int i = 0; i < 4; ++i) {
        float li = __shfl(l_run, 4 * lq + i);
        float inv = 1.f / li;
        int row = q0 + w * 16 + 4 * lq + i;
        unsigned short* op = o + (tokbase + row) * 768 + h * 64 + l16;
        #pragma unroll
        for (int f = 0; f < 4; ++f)
            op[f * 16] = f2bf(oacc[f][i] * inv);
    }
}

// ---------- GEMM (m97 + 2-phase dbuf): C[M,N] = A[M,K] @ Bt[N,K]^T ----------
// BM=128, BK=32, 4 waves (2x2), global_load_lds 16B staging, double-buffered:
// issue next tile's loads BEFORE current tile's MFMA; one barrier per K-step.
template<int BN, bool GELU, bool OBF16>
__global__ __launch_bounds__(256) void gemm_bt_k(const unsigned short* __restrict__ A,
                                                 const unsigned short* __restrict__ Bt,
                                                 const float* __restrict__ bias,
                                                 const float* __restrict__ res,
                                                 void* __restrict__ Cv,
                                                 int M, int N, int K) {
    constexpr int FN = BN / 32;                 // B frags per wave
    __shared__ unsigned short lA[2][128 * 32];
    __shared__ unsigned short lB[2][BN * 32];
    int tid = threadIdx.x;
    int m0 = blockIdx.y * 128, n0 = blockIdx.x * BN;
    int w = tid >> 6, lane = tid & 63;
    int l16 = lane & 15, lq = lane >> 4;
    int wrow = (w >> 1) * 64, wcol = (w & 1) * (BN / 2);

    f32x4 acc[4][FN] = {};

    auto stage = [&](int buf, int k0) {
        #pragma unroll
        for (int i = 0; i < 2; ++i) {           // A tile: 512 chunks of 16B
            int ch = tid + i * 256;
            int r = ch >> 2, c = ch & 3;
            gload16(A + (size_t)(m0 + r) * K + k0 + c * 8, &lA[buf][ch * 8]);
        }
        #pragma unroll
        for (int i = 0; i < BN / 64; ++i) {     // B tile: BN*4 chunks
            int ch = tid + i * 256;
            int r = ch >> 2, c = ch & 3;
            gload16(Bt + (size_t)(n0 + r) * K + k0 + c * 8, &lB[buf][ch * 8]);
        }
    };

    const int nk = K >> 5;
    stage(0, 0);
    __syncthreads();
    int cur = 0;
    for (int t = 0; t < nk; ++t) {
        if (t + 1 < nk) stage(cur ^ 1, (t + 1) << 5);

        bf16x8 af[4], bfv[FN];
        #pragma unroll
        for (int fm = 0; fm < 4; ++fm)
            af[fm] = *(const bf16x8*)&lA[cur][(wrow + fm * 16 + l16) * 32 + lq * 8];
        #pragma unroll
        for (int fn = 0; fn < FN; ++fn)
            bfv[fn] = *(const bf16x8*)&lB[cur][(wcol + fn * 16 + l16) * 32 + lq * 8];
        #pragma unroll
        for (int fm = 0; fm < 4; ++fm)
            #pragma unroll
            for (int fn = 0; fn < FN; ++fn)
                acc[fm][fn] = __builtin_amdgcn_mfma_f32_16x16x32_bf16(af[fm], bfv[fn], acc[fm][fn], 0, 0, 0);
        __syncthreads();   // drains vmcnt(0): next tile's loads complete here
        cur ^= 1;
    }

    float* Cf = (float*)Cv;
    unsigned short* Cb = (unsigned short*)Cv;
    #pragma unroll
    for (int fm = 0; fm < 4; ++fm)
        #pragma unroll
        for (int fn = 0; fn < FN; ++fn) {
            int col = n0 + wcol + fn * 16 + l16;
            float bv = bias ? bias[col] : 0.f;
            #pragma unroll
            for (int i = 0; i < 4; ++i) {
                int row = m0 + wrow + fm * 16 + 4 * lq + i;
                if (row < M) {
                    float v = acc[fm][fn][i] + bv;
                    if (GELU) v = 0.5f * v * (1.0f + erff(v * 0.70710678118f));
                    if (res)  v += res[(size_t)row * N + col];
                    if (OBF16) Cb[(size_t)row * N + col] = f2bf(v);
                    else       Cf[(size_t)row * N + col] = v;
                }
            }
        }
}

// ---------- launch ----------
extern "C" void kernel_launch(void* const* d_in, const int* in_sizes, int n_in,
                              void* d_out, int out_size, void* d_ws, size_t ws_size,
                              hipStream_t stream) {
    const float* filaments = (const float*)d_in[0];
    const float* mask      = (const float*)d_in[1];
    const float* ln_p1_g   = (const float*)d_in[2];
    const float* ln_p1_b   = (const float*)d_in[3];
    const float* W_patch   = (const float*)d_in[4];
    const float* b_patch   = (const float*)d_in[5];
    const float* ln_p2_g   = (const float*)d_in[6];
    const float* ln_p2_b   = (const float*)d_in[7];
    const float* peg_w     = (const float*)d_in[8];
    const float* peg_b     = (const float*)d_in[9];
    const float* cls_token = (const float*)d_in[10];
    const float* ln_a_g    = (const float*)d_in[11];
    const float* ln_a_b    = (const float*)d_in[12];
    const float* W_qkv     = (const float*)d_in[13];
    const float* W_o       = (const float*)d_in[14];
    const float* b_o       = (const float*)d_in[15];
    const float* inv_freq  = (const float*)d_in[16];
    const float* ln_f_g    = (const float*)d_in[17];
    const float* ln_f_b    = (const float*)d_in[18];
    const float* W1        = (const float*)d_in[19];
    const float* b1        = (const float*)d_in[20];
    const float* W2        = (const float*)d_in[21];
    const float* b2        = (const float*)d_in[22];

    // ---- workspace layout (~39 MB) ----
    char* p = (char*)d_ws;
    float* xa            = (float*)p;          p += 2048 * 768 * 4;
    float* xb            = (float*)p;          p += 2048 * 768 * 4;
    unsigned short* h_bf = (unsigned short*)p; p += 2048 * 768 * 2;
    unsigned short* qkv  = (unsigned short*)p; p += 2048 * 3072 * 2;   // qkv / m_bf overlay
    unsigned short* wbuf = (unsigned short*)p; p += 3072 * 768 * 2;    // per-layer W1t/W2t
    unsigned short* wqt  = (unsigned short*)p; p += 2304 * 768 * 2;
    unsigned short* wot  = (unsigned short*)p; p += 768 * 768 * 2;
    unsigned short* wpt  = (unsigned short*)p; p += 768 * 768 * 2;
    unsigned char* flags = (unsigned char*)p;  p += 8192;
    unsigned short* m_bf = qkv;
    float* tmp = (float*)qkv;                  // patch GEMM f32 out
    float* out = (float*)d_out;

    // ---- one-time precomputes ----
    mask_flags_k<<<6144, 256, 0, stream>>>(mask, flags);
    wt_cast_k<<<dim3(12, 12), 256, 0, stream>>>(W_patch, wpt, 768, 768);
    wt_cast_k<<<dim3(36, 12), 256, 0, stream>>>(W_qkv,  wqt, 768, 2304);
    wt_cast_k<<<dim3(12, 12), 256, 0, stream>>>(W_o,    wot, 768, 768);

    // ---- patch embed ----
    ln768_bf_k<<<2048, 256, 0, stream>>>(filaments, ln_p1_g, ln_p1_b, h_bf, 2046);
    gemm_bt_k<64, false, false><<<dim3(12, 16), 256, 0, stream>>>(h_bf, wpt, b_patch, nullptr, tmp, 2046, 768, 768);
    ln768_k<<<2046, 256, 0, stream>>>(tmp, ln_p2_g, ln_p2_b, xa, 1);
    cls_k<<<2, 256, 0, stream>>>(cls_token, xa);
    peg_k<<<2048, 256, 0, stream>>>(xa, peg_w, peg_b, xb);

    float* cur = xb;
    float* nxt = xa;
    for (int i = 0; i < 6; ++i) {
        ln768_bf_k<<<2048, 256, 0, stream>>>(cur, ln_a_g + i * 768, ln_a_b + i * 768, h_bf, 2048);
        gemm_bt_k<128, false, true><<<dim3(18, 16), 256, 0, stream>>>(h_bf, wqt, nullptr, nullptr, qkv, 2048, 2304, 768);
        rope_bf_k<<<2048, 384, 0, stream>>>(qkv, inv_freq);
        attn_mfma_k<<<dim3(16, 24), 256, 0, stream>>>(qkv, mask, flags, h_bf);
        gemm_bt_k<64, false, false><<<dim3(12, 16), 256, 0, stream>>>(h_bf, wot, b_o, cur, nxt, 2048, 768, 768);
        ln768_bf_k<<<2048, 256, 0, stream>>>(nxt, ln_f_g + i * 768, ln_f_b + i * 768, h_bf, 2048);
        wt_cast_k<<<dim3(48, 12), 256, 0, stream>>>(W1 + (size_t)i * 768 * 3072, wbuf, 768, 3072);
        gemm_bt_k<128, true, true><<<dim3(24, 16), 256, 0, stream>>>(h_bf, wbuf, b1 + i * 3072, nullptr, m_bf, 2048, 3072, 768);
        wt_cast_k<<<dim3(12, 48), 256, 0, stream>>>(W2 + (size_t)i * 3072 * 768, wbuf, 3072, 768);
        gemm_bt_k<64, false, false><<<dim3(12, 16), 256, 0, stream>>>(m_bf, wbuf, b2 + i * 768, nxt, (i == 5) ? out : cur, 2048, 768, 3072);
    }
}

// Round 5
// 1021.979 us; speedup vs baseline: 10.6514x; 1.3146x over previous
//
#include <hip/hip_runtime.h>
#include <hip/hip_bf16.h>
#include <math.h>

// ---------- types ----------
typedef __attribute__((ext_vector_type(8))) short          bf16x8;
typedef __attribute__((ext_vector_type(8))) unsigned short ushort8;
typedef __attribute__((ext_vector_type(4))) float          f32x4;

__device__ __forceinline__ unsigned short f2bf(float f) {
    union { float f; unsigned u; } v; v.f = f;
    unsigned u = v.u;
    unsigned r = (u + 0x7FFFu + ((u >> 16) & 1u)) >> 16;   // RNE
    return (unsigned short)r;
}
__device__ __forceinline__ float bf2f(unsigned short h) {
    union { unsigned u; float f; } v; v.u = ((unsigned)h) << 16;
    return v.f;
}

// async global->LDS, 16B per lane (m97 pattern)
__device__ __forceinline__ void gload16(const void* g, void* l) {
    __builtin_amdgcn_global_load_lds(
        (const __attribute__((address_space(1))) void*)g,
        (__attribute__((address_space(3))) void*)l, 16, 0, 0);
}

// ---------- weight transpose-cast: in[K][N] f32 -> out[N][K] bf16 ----------
__global__ __launch_bounds__(256) void wt_cast_k(const float* __restrict__ in,
                                                 unsigned short* __restrict__ out,
                                                 int K, int N) {
    __shared__ float t[64][65];
    int n0 = blockIdx.x * 64, k0 = blockIdx.y * 64;
    int tx = threadIdx.x & 63, ty = threadIdx.x >> 6;
    #pragma unroll
    for (int p = 0; p < 16; ++p) {
        int k = ty + p * 4;
        t[k][tx] = in[(size_t)(k0 + k) * N + n0 + tx];
    }
    __syncthreads();
    #pragma unroll
    for (int p = 0; p < 16; ++p) {
        int n = ty + p * 4;
        out[(size_t)(n0 + n) * K + k0 + tx] = f2bf(t[tx][n]);
    }
}

// ---------- mask triviality flags: 1 if 64x64 block of mask is all ones ----------
__global__ __launch_bounds__(256) void mask_flags_k(const float* __restrict__ mask,
                                                    unsigned char* __restrict__ flags) {
    int idx = blockIdx.x;                    // (bh*16 + qt)*16 + kt
    int tid = threadIdx.x;
    int kt = idx & 15, qt = (idx >> 4) & 15, bh = idx >> 8;
    int r = tid >> 2, cc = (tid & 3) * 16;
    const float* prow = mask + ((size_t)bh * 1024 + (size_t)qt * 64 + r) * 1024 + kt * 64 + cc;
    int bad = 0;
    #pragma unroll
    for (int j = 0; j < 4; ++j) {
        float4 v = *(const float4*)(prow + j * 4);
        bad |= (v.x != 1.f) || (v.y != 1.f) || (v.z != 1.f) || (v.w != 1.f);
    }
    __shared__ int sb[4];
    unsigned long long anyb = __ballot(bad != 0);
    if ((tid & 63) == 0) sb[tid >> 6] = (anyb != 0ull) ? 1 : 0;
    __syncthreads();
    if (tid == 0) flags[idx] = (unsigned char)(!(sb[0] | sb[1] | sb[2] | sb[3]));
}

// ---------- LayerNorm 768, f32 in -> bf16 out (pad rows >= Mvalid zeroed) ----------
__global__ __launch_bounds__(256) void ln768_bf_k(const float* __restrict__ in,
                                                  const float* __restrict__ g,
                                                  const float* __restrict__ b,
                                                  unsigned short* __restrict__ out,
                                                  int Mvalid) {
    int r = blockIdx.x, tid = threadIdx.x;
    unsigned short* y = out + (size_t)r * 768;
    if (r >= Mvalid) { y[tid] = 0; y[tid + 256] = 0; y[tid + 512] = 0; return; }
    const float* x = in + (size_t)r * 768;
    float v0 = x[tid], v1 = x[tid + 256], v2 = x[tid + 512];
    __shared__ float red[4];
    float s = v0 + v1 + v2;
    #pragma unroll
    for (int off = 32; off > 0; off >>= 1) s += __shfl_down(s, off);
    if ((tid & 63) == 0) red[tid >> 6] = s;
    __syncthreads();
    float mean = (red[0] + red[1] + red[2] + red[3]) * (1.0f / 768.0f);
    float d0 = v0 - mean, d1 = v1 - mean, d2 = v2 - mean;
    float q = d0 * d0 + d1 * d1 + d2 * d2;
    __syncthreads();
    #pragma unroll
    for (int off = 32; off > 0; off >>= 1) q += __shfl_down(q, off);
    if ((tid & 63) == 0) red[tid >> 6] = q;
    __syncthreads();
    float var = (red[0] + red[1] + red[2] + red[3]) * (1.0f / 768.0f);
    float rs = rsqrtf(var + 1e-5f);
    y[tid]       = f2bf(d0 * rs * g[tid]       + b[tid]);
    y[tid + 256] = f2bf(d1 * rs * g[tid + 256] + b[tid + 256]);
    y[tid + 512] = f2bf(d2 * rs * g[tid + 512] + b[tid + 512]);
}

// ---------- LayerNorm 768, f32 in -> f32 out (remap option for patch rows) ----------
__global__ __launch_bounds__(256) void ln768_k(const float* __restrict__ in,
                                               const float* __restrict__ g,
                                               const float* __restrict__ b,
                                               float* __restrict__ out,
                                               int remap) {
    int r = blockIdx.x, tid = threadIdx.x;
    const float* x = in + (size_t)r * 768;
    float v0 = x[tid], v1 = x[tid + 256], v2 = x[tid + 512];
    __shared__ float red[4];
    float s = v0 + v1 + v2;
    #pragma unroll
    for (int off = 32; off > 0; off >>= 1) s += __shfl_down(s, off);
    if ((tid & 63) == 0) red[tid >> 6] = s;
    __syncthreads();
    float mean = (red[0] + red[1] + red[2] + red[3]) * (1.0f / 768.0f);
    float d0 = v0 - mean, d1 = v1 - mean, d2 = v2 - mean;
    float q = d0 * d0 + d1 * d1 + d2 * d2;
    __syncthreads();
    #pragma unroll
    for (int off = 32; off > 0; off >>= 1) q += __shfl_down(q, off);
    if ((tid & 63) == 0) red[tid >> 6] = q;
    __syncthreads();
    float var = (red[0] + red[1] + red[2] + red[3]) * (1.0f / 768.0f);
    float rs = rsqrtf(var + 1e-5f);
    int orow = remap ? ((r / 1023) * 1024 + 1 + (r % 1023)) : r;
    float* y = out + (size_t)orow * 768;
    y[tid]       = d0 * rs * g[tid]       + b[tid];
    y[tid + 256] = d1 * rs * g[tid + 256] + b[tid + 256];
    y[tid + 512] = d2 * rs * g[tid + 512] + b[tid + 512];
}

// ---------- cls token fill ----------
__global__ void cls_k(const float* __restrict__ cls, float* __restrict__ x) {
    int bi = blockIdx.x, tid = threadIdx.x;
    #pragma unroll
    for (int k = 0; k < 3; ++k)
        x[(size_t)bi * 1024 * 768 + tid + k * 256] = cls[tid + k * 256];
}

// ---------- depthwise conv1d (PEG) + residual + bias ----------
__global__ __launch_bounds__(256) void peg_k(const float* __restrict__ x,
                                             const float* __restrict__ w,
                                             const float* __restrict__ pb,
                                             float* __restrict__ y) {
    int r = blockIdx.x;
    int i = r & 1023;
    int tid = threadIdx.x;
    const float* xr = x + (size_t)r * 768;
    float* yr = y + (size_t)r * 768;
    #pragma unroll
    for (int k = 0; k < 3; ++k) {
        int d = tid + k * 256;
        float c  = xr[d];
        float lf = (i > 0)    ? xr[d - 768] : 0.f;
        float rt = (i < 1023) ? xr[d + 768] : 0.f;
        yr[d] = c + pb[d] + w[d * 3 + 0] * lf + w[d * 3 + 1] * c + w[d * 3 + 2] * rt;
    }
}

// ---------- RoPE on q and k halves of bf16 qkv, in place ----------
__global__ __launch_bounds__(384) void rope_bf_k(unsigned short* __restrict__ qkv,
                                                 const float* __restrict__ inv_freq) {
    int r = blockIdx.x;
    int t = r & 1023;
    int tid = threadIdx.x;
    int qk  = tid / 192;
    int rem = tid % 192;
    int hh  = rem / 16, p = rem % 16;
    unsigned short* base = qkv + (size_t)r * 2304 + qk * 768 + hh * 64;
    float x0 = bf2f(base[2 * p]), x1 = bf2f(base[2 * p + 1]);
    float fr = (float)t * inv_freq[p];
    float c = cosf(fr), sn = sinf(fr);
    base[2 * p]     = f2bf(x0 * c - x1 * sn);
    base[2 * p + 1] = f2bf(x1 * c + x0 * sn);
}

// ---------- MFMA flash attention (bf16 qkv in, bf16 o out) ----------
__global__ __launch_bounds__(256) void attn_mfma_k(const unsigned short* __restrict__ qkv,
                                                   const float* __restrict__ mask,
                                                   const unsigned char* __restrict__ flags,
                                                   unsigned short* __restrict__ o) {
    const int qt = blockIdx.x, bh = blockIdx.y;
    const int bi = bh / 12, h = bh % 12;
    const int tid = threadIdx.x;
    const int w = tid >> 6, lane = tid & 63;
    const int l16 = lane & 15, lq = lane >> 4;

    __shared__ unsigned short lK[64 * 64];   // K[k][d]  bf16, XOR-swizzled 128B rows
    __shared__ unsigned short lV[64 * 64];   // V^T[d][k] bf16, XOR-swizzled

    const int q0 = qt * 64;
    const size_t tokbase = (size_t)bi * 1024;
    const int qrow = q0 + w * 16 + l16;

    bf16x8 qb[2];
    {
        const unsigned short* qp = qkv + (tokbase + qrow) * 2304 + h * 64;
        qb[0] = *(const bf16x8*)(qp + lq * 8);
        qb[1] = *(const bf16x8*)(qp + 32 + lq * 8);
    }

    const float* mrow = mask + ((size_t)bh * 1024 + qrow) * 1024;
    const unsigned char* fl = flags + ((size_t)bh * 16 + qt) * 16;

    float m_run = -1e30f, l_run = 0.f;
    f32x4 oacc[4] = {};      // O[q = 4lq+i][d = 16f + l16]

    for (int kt = 0; kt < 16; ++kt) {
        const int k0 = kt * 64;
        const bool triv = fl[kt] != 0;
        {
            const unsigned short* krp = qkv + (tokbase + k0 + lane) * 2304 + 768 + h * 64 + w * 16;
            const unsigned short* vrp = krp + 768;
            ushort8 kA = *(const ushort8*)krp, kB = *(const ushort8*)(krp + 8);
            ushort8 vA = *(const ushort8*)vrp, vB = *(const ushort8*)(vrp + 8);
            int byA = lane * 128 + ((w * 32 +  0) ^ ((lane & 7) << 4));
            int byB = lane * 128 + ((w * 32 + 16) ^ ((lane & 7) << 4));
            *(ushort8*)((char*)lK + byA) = kA;
            *(ushort8*)((char*)lK + byB) = kB;
            #pragma unroll
            for (int j = 0; j < 16; ++j) {
                int row = w * 16 + j;
                int by = row * 128 + ((2 * lane) ^ ((row & 7) << 4));
                *(unsigned short*)((char*)lV + by) = (j < 8) ? (unsigned short)vA[j] : (unsigned short)vB[j - 8];
            }
        }
        __syncthreads();

        // ---- S^T = K @ Q^T ----
        f32x4 sacc[4] = {};
        #pragma unroll
        for (int f = 0; f < 4; ++f) {
            int krow = f * 16 + l16;
            #pragma unroll
            for (int s = 0; s < 2; ++s) {
                int by = krow * 128 + (((s * 64) + lq * 16) ^ ((krow & 7) << 4));
                bf16x8 af = *(const bf16x8*)((const char*)lK + by);
                sacc[f] = __builtin_amdgcn_mfma_f32_16x16x32_bf16(af, qb[s], sacc[f], 0, 0, 0);
            }
        }

        // ---- mask + scale + online softmax (lane-local q = l16) ----
        float pv[4][4];
        float smax = -1e30f;
        if (triv) {
            #pragma unroll
            for (int f = 0; f < 4; ++f) {
                pv[f][0] = sacc[f][0] * 0.125f;
                pv[f][1] = sacc[f][1] * 0.125f;
                pv[f][2] = sacc[f][2] * 0.125f;
                pv[f][3] = sacc[f][3] * 0.125f;
                smax = fmaxf(smax, fmaxf(fmaxf(pv[f][0], pv[f][1]), fmaxf(pv[f][2], pv[f][3])));
            }
        } else {
            #pragma unroll
            for (int f = 0; f < 4; ++f) {
                float4 mk = *(const float4*)(mrow + k0 + f * 16 + lq * 4);
                pv[f][0] = sacc[f][0] * 0.125f + (1.f - mk.x) * -1e9f;
                pv[f][1] = sacc[f][1] * 0.125f + (1.f - mk.y) * -1e9f;
                pv[f][2] = sacc[f][2] * 0.125f + (1.f - mk.z) * -1e9f;
                pv[f][3] = sacc[f][3] * 0.125f + (1.f - mk.w) * -1e9f;
                smax = fmaxf(smax, fmaxf(fmaxf(pv[f][0], pv[f][1]), fmaxf(pv[f][2], pv[f][3])));
            }
        }
        smax = fmaxf(smax, __shfl_xor(smax, 16));
        smax = fmaxf(smax, __shfl_xor(smax, 32));
        float m_new = fmaxf(m_run, smax);
        float fac = expf(m_run - m_new);
        float lsum = 0.f;
        #pragma unroll
        for (int f = 0; f < 4; ++f) {
            #pragma unroll
            for (int i = 0; i < 4; ++i) {
                pv[f][i] = expf(pv[f][i] - m_new);
                lsum += pv[f][i];
            }
        }
        lsum += __shfl_xor(lsum, 16);
        lsum += __shfl_xor(lsum, 32);
        l_run = l_run * fac + lsum;
        m_run = m_new;

        #pragma unroll
        for (int i = 0; i < 4; ++i) {
            float fi = __shfl(fac, 4 * lq + i);
            oacc[0][i] *= fi; oacc[1][i] *= fi; oacc[2][i] *= fi; oacc[3][i] *= fi;
        }

        unsigned wpk[4][2];
        #pragma unroll
        for (int f = 0; f < 4; ++f) {
            wpk[f][0] = (unsigned)f2bf(pv[f][0]) | ((unsigned)f2bf(pv[f][1]) << 16);
            wpk[f][1] = (unsigned)f2bf(pv[f][2]) | ((unsigned)f2bf(pv[f][3]) << 16);
        }

        // ---- O += P @ V ----
        #pragma unroll
        for (int s = 0; s < 2; ++s) {
            unsigned aw[4];
            #pragma unroll
            for (int t = 0; t < 4; ++t) {
                int src = (2 * (lq & 1) + (t >> 1)) * 16 + l16;
                unsigned lo = __shfl(wpk[2 * s][t & 1], src);
                unsigned hi = __shfl(wpk[2 * s + 1][t & 1], src);
                aw[t] = (lq >> 1) ? hi : lo;
            }
            union { unsigned u[4]; bf16x8 v; } pa;
            pa.u[0] = aw[0]; pa.u[1] = aw[1]; pa.u[2] = aw[2]; pa.u[3] = aw[3];
            #pragma unroll
            for (int f = 0; f < 4; ++f) {
                int drow = f * 16 + l16;
                int by = drow * 128 + (((s * 64) + lq * 16) ^ ((drow & 7) << 4));
                bf16x8 vb = *(const bf16x8*)((const char*)lV + by);
                oacc[f] = __builtin_amdgcn_mfma_f32_16x16x32_bf16(pa.v, vb, oacc[f], 0, 0, 0);
            }
        }
        __syncthreads();
    }

    #pragma unroll
    for (int i = 0; i < 4; ++i) {
        float li = __shfl(l_run, 4 * lq + i);
        float inv = 1.f / li;
        int row = q0 + w * 16 + 4 * lq + i;
        unsigned short* op = o + (tokbase + row) * 768 + h * 64 + l16;
        #pragma unroll
        for (int f = 0; f < 4; ++f)
            op[f * 16] = f2bf(oacc[f][i] * inv);
    }
}

// ---------- GEMM: C[M,N] = A[M,K] @ Bt[N,K]^T ----------
// BM=64, BK=64, 4 waves, global_load_lds 16B staging with inverse-swizzled
// SOURCE (linear LDS dest), XOR-swizzled ds_read (conflict-free 128B rows),
// 2-phase double buffer. BN=128: wave layout 1x4 (FM=4,FN=2);
// BN=64: 2x2 (FM=2,FN=2).
template<int BN, bool GELU, bool OBF16>
__global__ __launch_bounds__(256) void gemm_bt_k(const unsigned short* __restrict__ A,
                                                 const unsigned short* __restrict__ Bt,
                                                 const float* __restrict__ bias,
                                                 const float* __restrict__ res,
                                                 void* __restrict__ Cv,
                                                 int M, int N, int K) {
    constexpr int FM = (BN == 128) ? 4 : 2;
    constexpr int FN = 2;
    __shared__ unsigned short lA[2][64 * 64];
    __shared__ unsigned short lB[2][BN * 64];
    int tid = threadIdx.x;
    int m0 = blockIdx.y * 64, n0 = blockIdx.x * BN;
    int w = tid >> 6, lane = tid & 63;
    int l16 = lane & 15, lq = lane >> 4;
    int wrow = (BN == 128) ? 0 : (w >> 1) * 32;
    int wcol = (BN == 128) ? (w * 32) : ((w & 1) * 32);

    f32x4 acc[FM][FN] = {};

    // stage with inverse-swizzled global source; LDS stays linear.
    auto stage = [&](int buf, int k0) {
        #pragma unroll
        for (int i = 0; i < 2; ++i) {               // A: 512 chunks of 16B
            int ch = tid + i * 256;
            int r = ch >> 3, c = ch & 7;
            int cs = c ^ (r & 7);
            gload16(A + (size_t)(m0 + r) * K + k0 + cs * 8, &lA[buf][ch * 8]);
        }
        #pragma unroll
        for (int i = 0; i < BN / 32; ++i) {         // B: BN*8 chunks
            int ch = tid + i * 256;
            int r = ch >> 3, c = ch & 7;
            int cs = c ^ (r & 7);
            gload16(Bt + (size_t)(n0 + r) * K + k0 + cs * 8, &lB[buf][ch * 8]);
        }
    };

    const int nk = K >> 6;
    stage(0, 0);
    __syncthreads();
    int cur = 0;
    for (int t = 0; t < nk; ++t) {
        if (t + 1 < nk) stage(cur ^ 1, (t + 1) << 6);

        bf16x8 af[FM][2], bfv[FN][2];
        #pragma unroll
        for (int fm = 0; fm < FM; ++fm) {
            int row = wrow + fm * 16 + l16;
            #pragma unroll
            for (int ks = 0; ks < 2; ++ks) {
                int by = row * 128 + ((ks * 64 + lq * 16) ^ ((row & 7) << 4));
                af[fm][ks] = *(const bf16x8*)((const char*)&lA[cur][0] + by);
            }
        }
        #pragma unroll
        for (int fn = 0; fn < FN; ++fn) {
            int row = wcol + fn * 16 + l16;
            #pragma unroll
            for (int ks = 0; ks < 2; ++ks) {
                int by = row * 128 + ((ks * 64 + lq * 16) ^ ((row & 7) << 4));
                bfv[fn][ks] = *(const bf16x8*)((const char*)&lB[cur][0] + by);
            }
        }
        #pragma unroll
        for (int ks = 0; ks < 2; ++ks)
            #pragma unroll
            for (int fm = 0; fm < FM; ++fm)
                #pragma unroll
                for (int fn = 0; fn < FN; ++fn)
                    acc[fm][fn] = __builtin_amdgcn_mfma_f32_16x16x32_bf16(af[fm][ks], bfv[fn][ks], acc[fm][fn], 0, 0, 0);
        __syncthreads();   // drains vmcnt(0): next tile's loads complete here
        cur ^= 1;
    }

    float* Cf = (float*)Cv;
    unsigned short* Cb = (unsigned short*)Cv;
    #pragma unroll
    for (int fm = 0; fm < FM; ++fm)
        #pragma unroll
        for (int fn = 0; fn < FN; ++fn) {
            int col = n0 + wcol + fn * 16 + l16;
            float bv = bias ? bias[col] : 0.f;
            #pragma unroll
            for (int i = 0; i < 4; ++i) {
                int row = m0 + wrow + fm * 16 + 4 * lq + i;
                if (row < M) {
                    float v = acc[fm][fn][i] + bv;
                    if (GELU) v = 0.5f * v * (1.0f + erff(v * 0.70710678118f));
                    if (res)  v += res[(size_t)row * N + col];
                    if (OBF16) Cb[(size_t)row * N + col] = f2bf(v);
                    else       Cf[(size_t)row * N + col] = v;
                }
            }
        }
}

// ---------- launch ----------
extern "C" void kernel_launch(void* const* d_in, const int* in_sizes, int n_in,
                              void* d_out, int out_size, void* d_ws, size_t ws_size,
                              hipStream_t stream) {
    const float* filaments = (const float*)d_in[0];
    const float* mask      = (const float*)d_in[1];
    const float* ln_p1_g   = (const float*)d_in[2];
    const float* ln_p1_b   = (const float*)d_in[3];
    const float* W_patch   = (const float*)d_in[4];
    const float* b_patch   = (const float*)d_in[5];
    const float* ln_p2_g   = (const float*)d_in[6];
    const float* ln_p2_b   = (const float*)d_in[7];
    const float* peg_w     = (const float*)d_in[8];
    const float* peg_b     = (const float*)d_in[9];
    const float* cls_token = (const float*)d_in[10];
    const float* ln_a_g    = (const float*)d_in[11];
    const float* ln_a_b    = (const float*)d_in[12];
    const float* W_qkv     = (const float*)d_in[13];
    const float* W_o       = (const float*)d_in[14];
    const float* b_o       = (const float*)d_in[15];
    const float* inv_freq  = (const float*)d_in[16];
    const float* ln_f_g    = (const float*)d_in[17];
    const float* ln_f_b    = (const float*)d_in[18];
    const float* W1        = (const float*)d_in[19];
    const float* b1        = (const float*)d_in[20];
    const float* W2        = (const float*)d_in[21];
    const float* b2        = (const float*)d_in[22];

    // ---- workspace layout (~39 MB) ----
    char* p = (char*)d_ws;
    float* xa            = (float*)p;          p += 2048 * 768 * 4;
    float* xb            = (float*)p;          p += 2048 * 768 * 4;
    unsigned short* h_bf = (unsigned short*)p; p += 2048 * 768 * 2;
    unsigned short* qkv  = (unsigned short*)p; p += 2048 * 3072 * 2;   // qkv / m_bf overlay
    unsigned short* wbuf = (unsigned short*)p; p += 3072 * 768 * 2;    // per-layer W1t/W2t
    unsigned short* wqt  = (unsigned short*)p; p += 2304 * 768 * 2;
    unsigned short* wot  = (unsigned short*)p; p += 768 * 768 * 2;
    unsigned short* wpt  = (unsigned short*)p; p += 768 * 768 * 2;
    unsigned char* flags = (unsigned char*)p;  p += 8192;
    unsigned short* m_bf = qkv;
    float* tmp = (float*)qkv;                  // patch GEMM f32 out
    float* out = (float*)d_out;

    // ---- one-time precomputes ----
    mask_flags_k<<<6144, 256, 0, stream>>>(mask, flags);
    wt_cast_k<<<dim3(12, 12), 256, 0, stream>>>(W_patch, wpt, 768, 768);
    wt_cast_k<<<dim3(36, 12), 256, 0, stream>>>(W_qkv,  wqt, 768, 2304);
    wt_cast_k<<<dim3(12, 12), 256, 0, stream>>>(W_o,    wot, 768, 768);

    // ---- patch embed ----
    ln768_bf_k<<<2048, 256, 0, stream>>>(filaments, ln_p1_g, ln_p1_b, h_bf, 2046);
    gemm_bt_k<64, false, false><<<dim3(12, 32), 256, 0, stream>>>(h_bf, wpt, b_patch, nullptr, tmp, 2046, 768, 768);
    ln768_k<<<2046, 256, 0, stream>>>(tmp, ln_p2_g, ln_p2_b, xa, 1);
    cls_k<<<2, 256, 0, stream>>>(cls_token, xa);
    peg_k<<<2048, 256, 0, stream>>>(xa, peg_w, peg_b, xb);

    float* cur = xb;
    float* nxt = xa;
    for (int i = 0; i < 6; ++i) {
        ln768_bf_k<<<2048, 256, 0, stream>>>(cur, ln_a_g + i * 768, ln_a_b + i * 768, h_bf, 2048);
        gemm_bt_k<128, false, true><<<dim3(18, 32), 256, 0, stream>>>(h_bf, wqt, nullptr, nullptr, qkv, 2048, 2304, 768);
        rope_bf_k<<<2048, 384, 0, stream>>>(qkv, inv_freq);
        attn_mfma_k<<<dim3(16, 24), 256, 0, stream>>>(qkv, mask, flags, h_bf);
        gemm_bt_k<64, false, false><<<dim3(12, 32), 256, 0, stream>>>(h_bf, wot, b_o, cur, nxt, 2048, 768, 768);
        ln768_bf_k<<<2048, 256, 0, stream>>>(nxt, ln_f_g + i * 768, ln_f_b + i * 768, h_bf, 2048);
        wt_cast_k<<<dim3(48, 12), 256, 0, stream>>>(W1 + (size_t)i * 768 * 3072, wbuf, 768, 3072);
        gemm_bt_k<128, true, true><<<dim3(24, 32), 256, 0, stream>>>(h_bf, wbuf, b1 + i * 3072, nullptr, m_bf, 2048, 3072, 768);
        wt_cast_k<<<dim3(12, 48), 256, 0, stream>>>(W2 + (size_t)i * 3072 * 768, wbuf, 3072, 768);
        gemm_bt_k<64, false, false><<<dim3(12, 32), 256, 0, stream>>>(m_bf, wbuf, b2 + i * 768, nxt, (i == 5) ? out : cur, 2048, 768, 3072);
    }
}